// Round 1
// baseline (1854.046 us; speedup 1.0000x reference)
//
#include <hip/hip_runtime.h>
#include <stdint.h>

// ============================================================================
// CrossMultiHeadAttention (L=1024, N=8, E=1024, H=8) — full bf16 MFMA pipeline
//
// Stages (all on `stream`, all Bᵀ-layout GEMMs, K-contiguous both operands):
//  1. convert f32->bf16: query,key,value,Wqkv,Wo,Wout
//  2. q_bf[h][n][l][d]   = query · Wq_hᵀ + bq      (batch h,n)
//  3. k_bf[h][n][s][d]   = key   · Wk_hᵀ + bk
//  4. v_t [h][n][d][s]   = Wv_h · value_nᵀ + bv    (bias by ROW -> transposed V)
//  5. scores f32 -> d_out attn region (scale 1/32)
//  6. softmax rows in-place + bf16 copy P
//  7. ctx[h][n][l][d]    = P · v_tᵀ
//  8. concat[(l,n)][h*E+e] = ctx · Wo_hᵀ + bo
//  9. out = concat · Woutᵀ + bout  (f32 -> d_out)
//
// ws layout (u16 elems), 512 MiB total, with reuse:
//   qb,kb,vb (3x8.4M) | Wqkv_b 25.2M | Wo_b 8.4M | Wout_b 8.4M |
//   buf1 67M (q_bf -> P_bf) | buf2 67M (k_bf -> ctx) | buf3 67M (v_t -> concat)
// ============================================================================

typedef unsigned short u16;
typedef unsigned int u32;
typedef __attribute__((ext_vector_type(8))) __bf16 bf16x8;
typedef __attribute__((ext_vector_type(4))) float f32x4;
typedef __attribute__((ext_vector_type(4))) u16 u16x4;

#define DEVFN static __device__ __forceinline__

static constexpr int LQ = 1024, NN = 8, EE = 1024, HH = 8, SS = 1024;
static constexpr long LNE = (long)LQ * NN * EE;        // 8,388,608
static constexpr long W1  = (long)HH * 3 * EE * EE;    // 25,165,824
static constexpr long WEE = (long)HH * EE * EE;        // 8,388,608
static constexpr long BIG = (long)HH * NN * LQ * EE;   // 67,108,864

DEVFN u16 f2bf(float x) {  // RNE f32->bf16
  u32 u = __builtin_bit_cast(u32, x);
  u = (u + 0x7FFFu + ((u >> 16) & 1u)) >> 16;
  return (u16)u;
}

DEVFN void gload16(const void* g, void* l) {
  // CK-style "dirty" AS cast: generic->uintptr->AS1/AS3 (low 32 bits of a
  // generic LDS pointer are the LDS offset on gfx9+).
  __builtin_amdgcn_global_load_lds(
      (const __attribute__((address_space(1))) void*)(uintptr_t)g,
      (__attribute__((address_space(3))) void*)(uintptr_t)l, 16, 0, 0);
}

// ---------------- f32 -> bf16 convert ----------------
__global__ __launch_bounds__(256) void k_cvt(const float* __restrict__ x,
                                             u16* __restrict__ y, long n4) {
  long i = (long)blockIdx.x * blockDim.x + threadIdx.x;
  const long st = (long)gridDim.x * blockDim.x;
  for (; i < n4; i += st) {
    float4 v = reinterpret_cast<const float4*>(x)[i];
    u16x4 o;
    o.x = f2bf(v.x); o.y = f2bf(v.y); o.z = f2bf(v.z); o.w = f2bf(v.w);
    reinterpret_cast<u16x4*>(y)[i] = o;
  }
}

// ---------------- softmax over rows of 1024, in-place f32 + bf16 copy -------
__global__ __launch_bounds__(256) void k_softmax(float* __restrict__ S,
                                                 u16* __restrict__ P) {
  __shared__ float smax[4], ssum[4];
  const long row = blockIdx.x;
  float* sr = S + row * 1024;
  const int tid = threadIdx.x;
  float4 v = reinterpret_cast<const float4*>(sr)[tid];
  float m = fmaxf(fmaxf(v.x, v.y), fmaxf(v.z, v.w));
#pragma unroll
  for (int o = 1; o < 64; o <<= 1) m = fmaxf(m, __shfl_xor(m, o));
  const int wv = tid >> 6, ln = tid & 63;
  if (ln == 0) smax[wv] = m;
  __syncthreads();
  m = fmaxf(fmaxf(smax[0], smax[1]), fmaxf(smax[2], smax[3]));
  v.x = __expf(v.x - m); v.y = __expf(v.y - m);
  v.z = __expf(v.z - m); v.w = __expf(v.w - m);
  float s = v.x + v.y + v.z + v.w;
#pragma unroll
  for (int o = 1; o < 64; o <<= 1) s += __shfl_xor(s, o);
  if (ln == 0) ssum[wv] = s;
  __syncthreads();
  s = ssum[0] + ssum[1] + ssum[2] + ssum[3];
  const float inv = 1.0f / s;
  v.x *= inv; v.y *= inv; v.z *= inv; v.w *= inv;
  reinterpret_cast<float4*>(sr)[tid] = v;
  u16x4 o4;
  o4.x = f2bf(v.x); o4.y = f2bf(v.y); o4.z = f2bf(v.z); o4.w = f2bf(v.w);
  reinterpret_cast<u16x4*>(P + row * 1024)[tid] = o4;
}

// ---------------- batched Bᵀ GEMM, m97-style -------------------------------
// C[h,n] = A[h,n] (MxK, K-contig) · B[h,n]ᵀ (NxK, K-contig)  [*scale +bias]
// BM=BN=128, BK=64, 256 threads (4 waves, 2x2), 4x4 16x16x32 bf16 MFMA frags.
struct GemmP {
  const u16* A; const u16* B; const float* bias;
  float* Cf; u16* Cb;
  int lda, ldb, ldc, ldcb, K, NB;
  long sAh, sAn, sBh, sBn, sCh, sCn, sBiasH;
  float scale;
};

template <int HAS_BIAS, int BIAS_ROW, int OUT_F32, int OUT_BF16>
__global__ __launch_bounds__(256) void k_gemm_bt(GemmP p) {
  const int bz = blockIdx.z;
  const int h = bz / p.NB, n = bz % p.NB;
  const u16* Ab = p.A + (long)h * p.sAh + (long)n * p.sAn;
  const u16* Bb = p.B + (long)h * p.sBh + (long)n * p.sBn;
  const long coff = (long)h * p.sCh + (long)n * p.sCn;
  const int row0 = blockIdx.y * 128;
  const int col0 = blockIdx.x * 128;

  __shared__ u16 As[128 * 64];
  __shared__ u16 Bs[128 * 64];

  const int tid = threadIdx.x;
  const int wave = tid >> 6, lane = tid & 63;
  const int wr = wave >> 1, wc = wave & 1;

  f32x4 acc[4][4];
  const f32x4 zero = {0.f, 0.f, 0.f, 0.f};
#pragma unroll
  for (int i = 0; i < 4; ++i)
#pragma unroll
    for (int j = 0; j < 4; ++j) acc[i][j] = zero;

  // staging coords: wave covers rows [wave*32, wave*32+32), 4 instrs x 8 rows
  const int sr = wave * 32 + (lane >> 3);
  const int sc = (lane & 7) * 8;
  const u16* agp = Ab + (long)(row0 + sr) * p.lda + sc;
  const u16* bgp = Bb + (long)(col0 + sr) * p.ldb + sc;
  u16* asl = &As[wave * 2048];  // 4KB per wave chunk
  u16* bsl = &Bs[wave * 2048];

  const int nkt = p.K >> 6;
  for (int kt = 0; kt < nkt; ++kt) {
    __syncthreads();  // previous compute done before overwriting LDS
#pragma unroll
    for (int i = 0; i < 4; ++i) {
      gload16(agp + (long)i * 8 * p.lda, asl + i * 512);
      gload16(bgp + (long)i * 8 * p.ldb, bsl + i * 512);
    }
    agp += 64; bgp += 64;
    __syncthreads();  // drains vmcnt -> LDS tiles ready
#pragma unroll
    for (int kk = 0; kk < 2; ++kk) {
      bf16x8 af[4], bfr[4];
#pragma unroll
      for (int mi = 0; mi < 4; ++mi) {
        const int r = wr * 64 + mi * 16 + (lane & 15);
        af[mi] = *reinterpret_cast<const bf16x8*>(
            &As[r * 64 + kk * 32 + ((lane >> 4) * 8)]);
      }
#pragma unroll
      for (int ni = 0; ni < 4; ++ni) {
        const int c = wc * 64 + ni * 16 + (lane & 15);
        bfr[ni] = *reinterpret_cast<const bf16x8*>(
            &Bs[c * 64 + kk * 32 + ((lane >> 4) * 8)]);
      }
#pragma unroll
      for (int mi = 0; mi < 4; ++mi)
#pragma unroll
        for (int ni = 0; ni < 4; ++ni)
          acc[mi][ni] = __builtin_amdgcn_mfma_f32_16x16x32_bf16(
              af[mi], bfr[ni], acc[mi][ni], 0, 0, 0);
    }
  }

  // epilogue: C row = (lane>>4)*4 + j, col = lane&15 (m89-verified layout)
  const int crow = (lane >> 4) * 4;
  const int ccol = lane & 15;
#pragma unroll
  for (int mi = 0; mi < 4; ++mi) {
#pragma unroll
    for (int j = 0; j < 4; ++j) {
      const int grow = row0 + wr * 64 + mi * 16 + crow + j;
#pragma unroll
      for (int ni = 0; ni < 4; ++ni) {
        const int gcol = col0 + wc * 64 + ni * 16 + ccol;
        float v = acc[mi][ni][j] * p.scale;
        if constexpr (HAS_BIAS) {
          v += p.bias[(long)h * p.sBiasH + (BIAS_ROW ? grow : gcol)];
        }
        if constexpr (OUT_F32)
          p.Cf[coff + (long)grow * p.ldc + gcol] = v;
        if constexpr (OUT_BF16)
          p.Cb[coff + (long)grow * p.ldcb + gcol] = f2bf(v);
      }
    }
  }
}

// ============================================================================
extern "C" void kernel_launch(void* const* d_in, const int* in_sizes, int n_in,
                              void* d_out, int out_size, void* d_ws,
                              size_t ws_size, hipStream_t stream) {
  const float* query = (const float*)d_in[0];
  const float* key_  = (const float*)d_in[1];
  const float* value = (const float*)d_in[2];
  const float* Wqkv  = (const float*)d_in[3];
  const float* bqkv  = (const float*)d_in[4];
  const float* Wo    = (const float*)d_in[5];
  const float* bo    = (const float*)d_in[6];
  const float* Wout  = (const float*)d_in[7];
  const float* bout  = (const float*)d_in[8];

  float* out  = (float*)d_out;      // (L,N,E) f32
  float* attn = out + LNE;          // (H,N,L,S) f32

  u16* qb    = (u16*)d_ws;
  u16* kb    = qb + LNE;
  u16* vb    = kb + LNE;
  u16* wq    = vb + LNE;            // Wqkv bf16 (H,3E,E)
  u16* wob   = wq + W1;
  u16* woutb = wob + WEE;
  u16* buf1  = woutb + WEE;         // q_bf  -> P_bf
  u16* buf2  = buf1 + BIG;          // k_bf  -> ctx_bf
  u16* buf3  = buf2 + BIG;          // v_t   -> concat
  // total = 512 MiB; assumes ws_size >= 536,870,912

  // -------- converts --------
  k_cvt<<<2048, 256, 0, stream>>>(query, qb, LNE / 4);
  k_cvt<<<2048, 256, 0, stream>>>(key_, kb, LNE / 4);
  k_cvt<<<2048, 256, 0, stream>>>(value, vb, LNE / 4);
  k_cvt<<<2048, 256, 0, stream>>>(Wqkv, wq, W1 / 4);
  k_cvt<<<2048, 256, 0, stream>>>(Wo, wob, WEE / 4);
  k_cvt<<<2048, 256, 0, stream>>>(Wout, woutb, WEE / 4);

  const dim3 blk(256);
  const dim3 g64(EE / 128, LQ / 128, HH * NN);

  // -------- q projection: buf1[h][n][l][d] --------
  {
    GemmP p = {};
    p.A = qb;  p.lda = NN * EE; p.sAh = 0;            p.sAn = EE;
    p.B = wq;  p.ldb = EE;      p.sBh = 3L * EE * EE; p.sBn = 0;
    p.bias = bqkv; p.sBiasH = 3 * EE;
    p.Cb = buf1; p.ldcb = EE; p.sCh = (long)NN * LQ * EE; p.sCn = (long)LQ * EE;
    p.K = EE; p.NB = NN; p.scale = 1.f;
    k_gemm_bt<1, 0, 0, 1><<<g64, blk, 0, stream>>>(p);
  }
  // -------- k projection: buf2[h][n][s][d] --------
  {
    GemmP p = {};
    p.A = kb;            p.lda = NN * EE; p.sAh = 0;            p.sAn = EE;
    p.B = wq + (long)EE * EE; p.ldb = EE; p.sBh = 3L * EE * EE; p.sBn = 0;
    p.bias = bqkv + EE; p.sBiasH = 3 * EE;
    p.Cb = buf2; p.ldcb = EE; p.sCh = (long)NN * LQ * EE; p.sCn = (long)LQ * EE;
    p.K = EE; p.NB = NN; p.scale = 1.f;
    k_gemm_bt<1, 0, 0, 1><<<g64, blk, 0, stream>>>(p);
  }
  // -------- v projection (transposed): buf3[h][n][d][s] = Wv_h · value_nᵀ ---
  {
    GemmP p = {};
    p.A = wq + 2L * EE * EE; p.lda = EE;      p.sAh = 3L * EE * EE; p.sAn = 0;
    p.B = vb;                p.ldb = NN * EE; p.sBh = 0;            p.sBn = EE;
    p.bias = bqkv + 2 * EE; p.sBiasH = 3 * EE;  // bias indexed by ROW (=d)
    p.Cb = buf3; p.ldcb = SS; p.sCh = (long)NN * EE * SS; p.sCn = (long)EE * SS;
    p.K = EE; p.NB = NN; p.scale = 1.f;
    k_gemm_bt<1, 1, 0, 1><<<g64, blk, 0, stream>>>(p);
  }
  // -------- scores: attn[h][n][l][s] (f32) = q·kᵀ / 32 --------
  {
    GemmP p = {};
    p.A = buf1; p.lda = EE; p.sAh = (long)NN * LQ * EE; p.sAn = (long)LQ * EE;
    p.B = buf2; p.ldb = EE; p.sBh = (long)NN * LQ * EE; p.sBn = (long)LQ * EE;
    p.Cf = attn; p.ldc = SS; p.sCh = (long)NN * LQ * SS; p.sCn = (long)LQ * SS;
    p.K = EE; p.NB = NN; p.scale = 1.f / 32.f;
    k_gemm_bt<0, 0, 1, 0><<<g64, blk, 0, stream>>>(p);
  }
  // -------- softmax in-place + bf16 P into buf1 (q_bf dead) --------
  k_softmax<<<HH * NN * LQ, 256, 0, stream>>>(attn, buf1);
  // -------- ctx: buf2[h][n][l][d] = P · v_tᵀ (k_bf dead) --------
  {
    GemmP p = {};
    p.A = buf1; p.lda = SS; p.sAh = (long)NN * LQ * SS; p.sAn = (long)LQ * SS;
    p.B = buf3; p.ldb = SS; p.sBh = (long)NN * EE * SS; p.sBn = (long)EE * SS;
    p.Cb = buf2; p.ldcb = EE; p.sCh = (long)NN * LQ * EE; p.sCn = (long)LQ * EE;
    p.K = SS; p.NB = NN; p.scale = 1.f;
    k_gemm_bt<0, 0, 0, 1><<<g64, blk, 0, stream>>>(p);
  }
  // -------- head_out -> concat buf3[(l*NN+n)][h*EE+e] (v_t dead) --------
  {
    GemmP p = {};
    p.A = buf2; p.lda = EE; p.sAh = (long)NN * LQ * EE; p.sAn = (long)LQ * EE;
    p.B = wob;  p.ldb = EE; p.sBh = (long)EE * EE;      p.sBn = 0;
    p.bias = bo; p.sBiasH = EE;
    p.Cb = buf3; p.ldcb = NN * HH * EE;  // 65536
    p.sCh = EE; p.sCn = (long)HH * EE;
    p.K = EE; p.NB = NN; p.scale = 1.f;
    k_gemm_bt<1, 0, 0, 1><<<g64, blk, 0, stream>>>(p);
  }
  // -------- out = concat · Woutᵀ + bout (f32 -> d_out) --------
  {
    GemmP p = {};
    p.A = buf3;  p.lda = HH * EE; p.sAh = 0; p.sAn = 0;
    p.B = woutb; p.ldb = HH * EE; p.sBh = 0; p.sBn = 0;
    p.bias = bout; p.sBiasH = 0;
    p.Cf = out; p.ldc = EE; p.sCh = 0; p.sCn = 0;
    p.K = HH * EE; p.NB = 1; p.scale = 1.f;
    k_gemm_bt<1, 0, 1, 0><<<dim3(EE / 128, (LQ * NN) / 128, 1), blk, 0, stream>>>(p);
  }
}

// Round 2
// 1144.094 us; speedup vs baseline: 1.6205x; 1.6205x over previous
//
#include <hip/hip_runtime.h>
#include <stdint.h>

// ============================================================================
// CrossMultiHeadAttention (L=1024, N=8, E=1024, H=8)
// 256x256-tile 8-phase pipelined bf16 MFMA GEMM (T1+T2+T3+T4+T5) + merged tail.
//
// Pipeline math (per-wave, 2 gload_lds per half-tile, halves orderd A0,B0,A1,B1):
//   stage depth D=5 (prologue stages halves 0..4), vmcnt(2) once per K-tile.
//   RAW: at phase 4t-1, issued halves <= 4t+4, vmcnt(2) -> halves <= 4t+3 done
//        == all of tile t, before tile t's first ds_read at phase 4t.  OK
//   WAR: half of tile t+2 (same LDS buf as t) issues at phase >= 4t+3, which is
//        after the barrier ending phase 4t+2 = last ds_read of tile t.  OK
// ============================================================================

typedef unsigned short u16;
typedef unsigned int u32;
typedef __attribute__((ext_vector_type(8))) __bf16 bf16x8;
typedef __attribute__((ext_vector_type(4))) float f32x4;
typedef __attribute__((ext_vector_type(4))) u16 u16x4;

#define DEVFN static __device__ __forceinline__

static constexpr int LQ = 1024, NN = 8, EE = 1024, HH = 8, SS = 1024;
static constexpr long LNE = (long)LQ * NN * EE;        // 8,388,608
static constexpr long W1  = (long)HH * 3 * EE * EE;    // 25,165,824
static constexpr long WEE = (long)HH * EE * EE;        // 8,388,608
static constexpr long BIG = (long)HH * NN * LQ * EE;   // 67,108,864

DEVFN u16 f2bf(float x) {  // RNE f32->bf16
  u32 u = __builtin_bit_cast(u32, x);
  u = (u + 0x7FFFu + ((u >> 16) & 1u)) >> 16;
  return (u16)u;
}

DEVFN void gload16(const u16* g, u16* l) {
  __builtin_amdgcn_global_load_lds(
      (const __attribute__((address_space(1))) void*)(uintptr_t)g,
      (__attribute__((address_space(3))) void*)(uintptr_t)l, 16, 0, 0);
}

// ---------------- f32 -> bf16 convert ----------------
__global__ __launch_bounds__(256) void k_cvt(const float* __restrict__ x,
                                             u16* __restrict__ y, long n4) {
  long i = (long)blockIdx.x * blockDim.x + threadIdx.x;
  const long st = (long)gridDim.x * blockDim.x;
  for (; i < n4; i += st) {
    float4 v = reinterpret_cast<const float4*>(x)[i];
    u16x4 o;
    o.x = f2bf(v.x); o.y = f2bf(v.y); o.z = f2bf(v.z); o.w = f2bf(v.w);
    reinterpret_cast<u16x4*>(y)[i] = o;
  }
}

// ---------------- transpose-convert Wo (h,e,d) f32 -> WoT (h,d,e) bf16 ------
__global__ __launch_bounds__(256) void k_cvt_t(const float* __restrict__ Wo,
                                               u16* __restrict__ WoT) {
  __shared__ float t[64][65];
  const float* src =
      Wo + ((long)blockIdx.z * 1024 + blockIdx.y * 64) * 1024 + blockIdx.x * 64;
  const int r = threadIdx.x >> 4, c4 = (threadIdx.x & 15) * 4;
#pragma unroll
  for (int rr = 0; rr < 64; rr += 16) {
    float4 v = *reinterpret_cast<const float4*>(&src[(long)(r + rr) * 1024 + c4]);
    t[r + rr][c4] = v.x; t[r + rr][c4 + 1] = v.y;
    t[r + rr][c4 + 2] = v.z; t[r + rr][c4 + 3] = v.w;
  }
  __syncthreads();
  u16* dst =
      WoT + ((long)blockIdx.z * 1024 + blockIdx.x * 64) * 1024 + blockIdx.y * 64;
#pragma unroll
  for (int rr = 0; rr < 64; rr += 16) {
    u16x4 o;
    o.x = f2bf(t[c4][r + rr]);     o.y = f2bf(t[c4 + 1][r + rr]);
    o.z = f2bf(t[c4 + 2][r + rr]); o.w = f2bf(t[c4 + 3][r + rr]);
    *reinterpret_cast<u16x4*>(&dst[(long)(r + rr) * 1024 + c4]) = o;
  }
}

// ---------------- bias_eff[e] = bout[e] + sum_i bo_flat[i]*Wout[e][i] -------
__global__ __launch_bounds__(256) void k_bias_eff(const float* __restrict__ Wout,
                                                  const float* __restrict__ bo,
                                                  const float* __restrict__ bout,
                                                  float* __restrict__ be) {
  const int e = blockIdx.x;
  const float* row = Wout + (long)e * 8192;
  float s = 0.f;
  for (int i = threadIdx.x; i < 8192; i += 256) s += row[i] * bo[i];
#pragma unroll
  for (int o = 1; o < 64; o <<= 1) s += __shfl_xor(s, o);
  __shared__ float ps[4];
  if ((threadIdx.x & 63) == 0) ps[threadIdx.x >> 6] = s;
  __syncthreads();
  if (threadIdx.x == 0) be[e] = bout[e] + ps[0] + ps[1] + ps[2] + ps[3];
}

// ---------------- out = p0 + p1 + be (split-K combine) ----------------------
__global__ __launch_bounds__(256) void k_combine(const float* __restrict__ p0,
                                                 const float* __restrict__ p1,
                                                 const float* __restrict__ be,
                                                 float* __restrict__ out) {
  long i = (long)blockIdx.x * 256 + threadIdx.x;
  const long st = (long)gridDim.x * 256;
  for (; i < 2097152; i += st) {
    float4 a = reinterpret_cast<const float4*>(p0)[i];
    float4 b = reinterpret_cast<const float4*>(p1)[i];
    float4 c = reinterpret_cast<const float4*>(be)[i & 255];
    float4 o = {a.x + b.x + c.x, a.y + b.y + c.y, a.z + b.z + c.z,
                a.w + b.w + c.w};
    reinterpret_cast<float4*>(out)[i] = o;
  }
}

// ---------------- softmax over rows of 1024, in-place f32 + bf16 copy -------
__global__ __launch_bounds__(256) void k_softmax(float* __restrict__ S,
                                                 u16* __restrict__ P) {
  __shared__ float smax[4], ssum[4];
  const long row = blockIdx.x;
  float* sr = S + row * 1024;
  const int tid = threadIdx.x;
  float4 v = reinterpret_cast<const float4*>(sr)[tid];
  float m = fmaxf(fmaxf(v.x, v.y), fmaxf(v.z, v.w));
#pragma unroll
  for (int o = 1; o < 64; o <<= 1) m = fmaxf(m, __shfl_xor(m, o));
  const int wv = tid >> 6, ln = tid & 63;
  if (ln == 0) smax[wv] = m;
  __syncthreads();
  m = fmaxf(fmaxf(smax[0], smax[1]), fmaxf(smax[2], smax[3]));
  v.x = __expf(v.x - m); v.y = __expf(v.y - m);
  v.z = __expf(v.z - m); v.w = __expf(v.w - m);
  float s = v.x + v.y + v.z + v.w;
#pragma unroll
  for (int o = 1; o < 64; o <<= 1) s += __shfl_xor(s, o);
  if (ln == 0) ssum[wv] = s;
  __syncthreads();
  s = ssum[0] + ssum[1] + ssum[2] + ssum[3];
  const float inv = 1.0f / s;
  v.x *= inv; v.y *= inv; v.z *= inv; v.w *= inv;
  reinterpret_cast<float4*>(sr)[tid] = v;
  u16x4 o4;
  o4.x = f2bf(v.x); o4.y = f2bf(v.y); o4.z = f2bf(v.z); o4.w = f2bf(v.w);
  reinterpret_cast<u16x4*>(P + row * 1024)[tid] = o4;
}

// ---------------- 256x256 8-phase batched B^T GEMM --------------------------
struct GemmP {
  const u16* A; const u16* B; const float* bias;
  float* Cf; u16* Cb;
  int lda, ldb, ldc, ldcb, K, NB;
  long sAh, sAn, sBh, sBn, sCh, sCn, sBiasH;
  float scale;
};

template <int M0, int N0>
DEVFN void quad(f32x4 (&acc)[8][4], bf16x8 (&a)[4][2], bf16x8 (&b)[4][2]) {
#pragma unroll
  for (int mi = 0; mi < 4; ++mi)
#pragma unroll
    for (int ni = 0; ni < 2; ++ni) {
      acc[M0 + mi][N0 + ni] = __builtin_amdgcn_mfma_f32_16x16x32_bf16(
          a[mi][0], b[N0 + ni][0], acc[M0 + mi][N0 + ni], 0, 0, 0);
      acc[M0 + mi][N0 + ni] = __builtin_amdgcn_mfma_f32_16x16x32_bf16(
          a[mi][1], b[N0 + ni][1], acc[M0 + mi][N0 + ni], 0, 0, 0);
    }
}

#define BAR() asm volatile("s_barrier" ::: "memory")
#define VMCNT2() asm volatile("s_waitcnt vmcnt(2)" ::: "memory")
#define VMCNT0() asm volatile("s_waitcnt vmcnt(0)" ::: "memory")
#define SB0() __builtin_amdgcn_sched_barrier(0)

template <int HAS_BIAS, int BIAS_ROW, int OUT_F32, int OUT_BF16>
__global__ __launch_bounds__(512, 2) void k_gemm256(GemmP p) {
  // ---- XCD-chunked block swizzle (all our grids are %8 == 0) ----
  long lid = blockIdx.x + (long)gridDim.x * (blockIdx.y + (long)gridDim.y * blockIdx.z);
  const long nwg = (long)gridDim.x * gridDim.y * gridDim.z;
  long s = (nwg % 8 == 0) ? ((lid % 8) * (nwg / 8) + lid / 8) : lid;
  const int bx = (int)(s % gridDim.x);
  long r2 = s / gridDim.x;
  const int by = (int)(r2 % gridDim.y);
  const int bz = (int)(r2 / gridDim.y);

  const int h = bz / p.NB, n = bz % p.NB;
  const u16* Ab = p.A + (long)h * p.sAh + (long)n * p.sAn;
  const u16* Bb = p.B + (long)h * p.sBh + (long)n * p.sBn;
  const long coff = (long)h * p.sCh + (long)n * p.sCn;
  const int row0 = by * 256;
  const int col0 = bx * 256;

  __shared__ u16 LDSU[65536];  // 128 KiB: A [2dbuf][2half][128][64] then B

  const int tid = threadIdx.x;
  const int wave = tid >> 6, lane = tid & 63;
  const int wr = wave >> 2, wc = wave & 3;
  const int NT = p.K >> 6;

  f32x4 acc[8][4];
  const f32x4 zero = {0.f, 0.f, 0.f, 0.f};
#pragma unroll
  for (int i = 0; i < 8; ++i)
#pragma unroll
    for (int j = 0; j < 4; ++j) acc[i][j] = zero;

  // staging: per half-tile a wave covers rows [wave*16, wave*16+16), 2 instrs.
  // global source column pre-swizzled: chunk = (lane&7) ^ ((lane>>3)&7).
  const int swc = ((lane & 7) ^ ((lane >> 3) & 7)) * 8;
  const u16* Ag = Ab + (long)(row0 + wave * 16 + (lane >> 3)) * p.lda + swc;
  const u16* Bg = Bb + (long)(col0 + wave * 16 + (lane >> 3)) * p.ldb + swc;

  auto STAGE = [&](int hh) {
    const int kt = hh >> 2;
    if (kt < NT) {
      const int pt = hh & 3;          // 0:A0 1:B0 2:A1 3:B1
      const int hf = pt >> 1;
      u16* l = &LDSU[((pt & 1) ? 32768 : 0) + (kt & 1) * 16384 + hf * 8192 +
                     wave * 1024];
      const int ld = (pt & 1) ? p.ldb : p.lda;
      const u16* g = ((pt & 1) ? Bg : Ag) + (long)hf * 128 * ld + kt * 64;
      gload16(g, l);
      gload16(g + 8L * ld, l + 512);
    }
  };

  // ---- prologue: stage halves 0..4, then guarantee tile 0 resident ----
  STAGE(0); STAGE(1); STAGE(2); STAGE(3); STAGE(4);
  VMCNT2();
  BAR();

  // ds_read swizzled chunk offsets (elems), kk = 0/1
  const int rA = lane & 15;
  const int c0 = (((lane >> 4)) ^ (lane & 7)) * 8;
  const int c1 = ((4 + (lane >> 4)) ^ (lane & 7)) * 8;

  bf16x8 a[4][2], b[4][2];

  for (int t = 0; t < NT; ++t) {
    const int db = (t & 1) * 16384;
    const u16* Ar = &LDSU[db + wr * 8192 + rA * 64];
    const u16* Br = &LDSU[32768 + db + (wc >> 1) * 8192 + ((wc & 1) * 64 + rA) * 64];

    // ---- phase 0: read a[0-3], b[0-1]; stage B0(t+1); mfma q0 ----
#pragma unroll
    for (int mi = 0; mi < 4; ++mi) {
      a[mi][0] = *reinterpret_cast<const bf16x8*>(&Ar[mi * 1024 + c0]);
      a[mi][1] = *reinterpret_cast<const bf16x8*>(&Ar[mi * 1024 + c1]);
    }
#pragma unroll
    for (int ni = 0; ni < 2; ++ni) {
      b[ni][0] = *reinterpret_cast<const bf16x8*>(&Br[ni * 1024 + c0]);
      b[ni][1] = *reinterpret_cast<const bf16x8*>(&Br[ni * 1024 + c1]);
    }
    STAGE(4 * t + 5);
    BAR();
    SB0(); __builtin_amdgcn_s_setprio(1);
    quad<0, 0>(acc, a, b);
    __builtin_amdgcn_s_setprio(0); SB0();
    BAR();

    // ---- phase 1: read b[2-3]; stage A1(t+1); mfma q1 ----
#pragma unroll
    for (int ni = 2; ni < 4; ++ni) {
      b[ni][0] = *reinterpret_cast<const bf16x8*>(&Br[ni * 1024 + c0]);
      b[ni][1] = *reinterpret_cast<const bf16x8*>(&Br[ni * 1024 + c1]);
    }
    STAGE(4 * t + 6);
    BAR();
    SB0(); __builtin_amdgcn_s_setprio(1);
    quad<0, 2>(acc, a, b);
    __builtin_amdgcn_s_setprio(0); SB0();
    BAR();

    // ---- phase 2: read a[4-7] (reuse regs); stage B1(t+1); mfma q2 ----
#pragma unroll
    for (int mi = 0; mi < 4; ++mi) {
      a[mi][0] = *reinterpret_cast<const bf16x8*>(&Ar[(4 + mi) * 1024 + c0]);
      a[mi][1] = *reinterpret_cast<const bf16x8*>(&Ar[(4 + mi) * 1024 + c1]);
    }
    STAGE(4 * t + 7);
    BAR();
    SB0(); __builtin_amdgcn_s_setprio(1);
    quad<4, 0>(acc, a, b);
    __builtin_amdgcn_s_setprio(0); SB0();
    BAR();

    // ---- phase 3: stage A0(t+2); counted vmcnt; mfma q3 ----
    STAGE(4 * t + 8);
    if (t < NT - 2) { VMCNT2(); }
    else if (t == NT - 2) { VMCNT0(); }
    BAR();
    SB0(); __builtin_amdgcn_s_setprio(1);
    quad<4, 2>(acc, a, b);
    __builtin_amdgcn_s_setprio(0); SB0();
    BAR();
  }

  // ---- epilogue: C row = (lane>>4)*4 + j, col = lane&15 ----
  const int crow = (lane >> 4) * 4;
  const int ccol = lane & 15;
#pragma unroll
  for (int mi = 0; mi < 8; ++mi) {
#pragma unroll
    for (int j = 0; j < 4; ++j) {
      const int grow = row0 + wr * 128 + mi * 16 + crow + j;
#pragma unroll
      for (int ni = 0; ni < 4; ++ni) {
        const int gcol = col0 + wc * 64 + ni * 16 + ccol;
        float v = acc[mi][ni][j] * p.scale;
        if constexpr (HAS_BIAS) {
          v += p.bias[(long)h * p.sBiasH + (BIAS_ROW ? grow : gcol)];
        }
        if constexpr (OUT_F32)
          p.Cf[coff + (long)grow * p.ldc + gcol] = v;
        if constexpr (OUT_BF16)
          p.Cb[coff + (long)grow * p.ldcb + gcol] = f2bf(v);
      }
    }
  }
}

// ============================================================================
extern "C" void kernel_launch(void* const* d_in, const int* in_sizes, int n_in,
                              void* d_out, int out_size, void* d_ws,
                              size_t ws_size, hipStream_t stream) {
  const float* query = (const float*)d_in[0];
  const float* key_  = (const float*)d_in[1];
  const float* value = (const float*)d_in[2];
  const float* Wqkv  = (const float*)d_in[3];
  const float* bqkv  = (const float*)d_in[4];
  const float* Wo    = (const float*)d_in[5];
  const float* bo    = (const float*)d_in[6];
  const float* Wout  = (const float*)d_in[7];
  const float* bout  = (const float*)d_in[8];

  float* out  = (float*)d_out;      // (L,N,E) f32
  float* attn = out + LNE;          // (H,N,L,S) f32

  // ws layout (u16 elems), exactly 512 MiB, with reuse:
  u16* qb    = (u16*)d_ws;          // query bf16 -> (after qproj) Bmat
  u16* kb    = qb + LNE;            // key bf16
  u16* vb    = kb + LNE;            // value bf16
  u16* wq    = vb + LNE;            // Wqkv bf16 (H,3E,E) -> (after vproj) be
  u16* woT   = wq + W1;             // Wo^T bf16 (H,E(d),E(e))
  u16* woutb = woT + WEE;           // Wout bf16 (E, H*E)
  u16* buf1  = woutb + WEE;         // q_bf  -> P_bf
  u16* buf2  = buf1 + BIG;          // k_bf  -> ctx_cat
  u16* buf3  = buf2 + BIG;          // v_t   -> split-K f32 partials
  u16* Bmat  = qb;                  // (E, H*E) bf16, reuses qb after qproj
  float* be  = (float*)wq;          // 1024 f32, reuses wq after vproj
  float* part = (float*)buf3;       // 2 x 8,388,608 f32

  // -------- converts --------
  k_cvt<<<2048, 256, 0, stream>>>(query, qb, LNE / 4);
  k_cvt<<<2048, 256, 0, stream>>>(key_, kb, LNE / 4);
  k_cvt<<<2048, 256, 0, stream>>>(value, vb, LNE / 4);
  k_cvt<<<2048, 256, 0, stream>>>(Wqkv, wq, W1 / 4);
  k_cvt<<<2048, 256, 0, stream>>>(Wout, woutb, WEE / 4);
  k_cvt_t<<<dim3(16, 16, 8), 256, 0, stream>>>(Wo, woT);

  const dim3 blk(512);
  const dim3 gsq(EE / 256, LQ / 256, HH * NN);  // (4,4,64) = 1024 WGs

  // -------- q projection: buf1[h][n][l][d] --------
  {
    GemmP p = {};
    p.A = qb;  p.lda = NN * EE; p.sAh = 0;            p.sAn = EE;
    p.B = wq;  p.ldb = EE;      p.sBh = 3L * EE * EE; p.sBn = 0;
    p.bias = bqkv; p.sBiasH = 3 * EE;
    p.Cb = buf1; p.ldcb = EE; p.sCh = (long)NN * LQ * EE; p.sCn = (long)LQ * EE;
    p.K = EE; p.NB = NN; p.scale = 1.f;
    k_gemm256<1, 0, 0, 1><<<gsq, blk, 0, stream>>>(p);
  }
  // -------- k projection: buf2[h][n][s][d] --------
  {
    GemmP p = {};
    p.A = kb;                 p.lda = NN * EE; p.sAh = 0;            p.sAn = EE;
    p.B = wq + (long)EE * EE; p.ldb = EE;      p.sBh = 3L * EE * EE; p.sBn = 0;
    p.bias = bqkv + EE; p.sBiasH = 3 * EE;
    p.Cb = buf2; p.ldcb = EE; p.sCh = (long)NN * LQ * EE; p.sCn = (long)LQ * EE;
    p.K = EE; p.NB = NN; p.scale = 1.f;
    k_gemm256<1, 0, 0, 1><<<gsq, blk, 0, stream>>>(p);
  }
  // -------- v projection (transposed): buf3[h][n][d][s] --------
  {
    GemmP p = {};
    p.A = wq + 2L * EE * EE; p.lda = EE;      p.sAh = 3L * EE * EE; p.sAn = 0;
    p.B = vb;                p.ldb = NN * EE; p.sBh = 0;            p.sBn = EE;
    p.bias = bqkv + 2 * EE; p.sBiasH = 3 * EE;  // bias by ROW (=d)
    p.Cb = buf3; p.ldcb = SS; p.sCh = (long)NN * EE * SS; p.sCn = (long)EE * SS;
    p.K = EE; p.NB = NN; p.scale = 1.f;
    k_gemm256<1, 1, 0, 1><<<gsq, blk, 0, stream>>>(p);
  }
  // -------- bias_eff (into wq region, now dead) --------
  k_bias_eff<<<1024, 256, 0, stream>>>(Wout, bo, bout, be);
  // -------- Bmat[e][h*E+d] = sum_e' Wout[e][h*E+e'] WoT[h][d][e'] (-> qb) ---
  {
    GemmP p = {};
    p.A = woutb; p.lda = HH * EE; p.sAh = EE;            p.sAn = 0;
    p.B = woT;   p.ldb = EE;      p.sBh = (long)EE * EE; p.sBn = 0;
    p.Cb = Bmat; p.ldcb = HH * EE; p.sCh = EE; p.sCn = 0;
    p.K = EE; p.NB = 1; p.scale = 1.f;
    k_gemm256<0, 0, 0, 1><<<dim3(4, 4, 8), blk, 0, stream>>>(p);
  }
  // -------- scores: attn[h][n][l][s] (f32) = q·k^T / 32 --------
  {
    GemmP p = {};
    p.A = buf1; p.lda = EE; p.sAh = (long)NN * LQ * EE; p.sAn = (long)LQ * EE;
    p.B = buf2; p.ldb = EE; p.sBh = (long)NN * LQ * EE; p.sBn = (long)LQ * EE;
    p.Cf = attn; p.ldc = SS; p.sCh = (long)NN * LQ * SS; p.sCn = (long)LQ * SS;
    p.K = EE; p.NB = NN; p.scale = 1.f / 32.f;
    k_gemm256<0, 0, 1, 0><<<gsq, blk, 0, stream>>>(p);
  }
  // -------- softmax in-place + bf16 P into buf1 (q dead) --------
  k_softmax<<<HH * NN * LQ, 256, 0, stream>>>(attn, buf1);
  // -------- ctx -> concat layout: buf2[(l*NN+n)][h*EE+d] (k dead) --------
  {
    GemmP p = {};
    p.A = buf1; p.lda = SS; p.sAh = (long)NN * LQ * SS; p.sAn = (long)LQ * SS;
    p.B = buf3; p.ldb = SS; p.sBh = (long)NN * EE * SS; p.sBn = (long)EE * SS;
    p.Cb = buf2; p.ldcb = NN * HH * EE;  // 65536
    p.sCh = EE; p.sCn = (long)HH * EE;
    p.K = SS; p.NB = NN; p.scale = 1.f;
    k_gemm256<0, 0, 0, 1><<<gsq, blk, 0, stream>>>(p);
  }
  // -------- final split-K=2: part[kc] = ctx_cat · Bmat^T (K=4096 each) -----
  {
    GemmP p = {};
    p.A = buf2; p.lda = HH * EE; p.sAh = 4096; p.sAn = 0;
    p.B = Bmat; p.ldb = HH * EE; p.sBh = 4096; p.sBn = 0;
    p.Cf = part; p.ldc = EE; p.sCh = (long)LQ * NN * EE; p.sCn = 0;
    p.K = 4096; p.NB = 1; p.scale = 1.f;
    k_gemm256<0, 0, 1, 0><<<dim3(EE / 256, LQ * NN / 256, 2), blk, 0, stream>>>(p);
  }
  // -------- combine: out = p0 + p1 + bias_eff --------
  k_combine<<<2048, 256, 0, stream>>>(part, part + LNE, be, out);
}

// Round 3
// 1003.505 us; speedup vs baseline: 1.8476x; 1.1401x over previous
//
#include <hip/hip_runtime.h>
#include <stdint.h>

// ============================================================================
// CrossMultiHeadAttention (L=1024, N=8, E=1024, H=8) — restructured pipeline.
//
// scores = (query·Gt^T)·key^T + a·row + b·col + c,  Gt = Wk^T·Wq   (saves q,k proj)
// out    = Σ_h (P·value)_h · F_h^T + be2,           F = (Wout·Wo)·Wv (saves 1 GEMM)
//
// GEMM engine: 256x256 tile, BK=64, 8-phase, global_load_lds + XOR swizzle,
// counted vmcnt(2), setprio around MFMA (unchanged from round 2).
// ============================================================================

typedef unsigned short u16;
typedef unsigned int u32;
typedef __attribute__((ext_vector_type(8))) __bf16 bf16x8;
typedef __attribute__((ext_vector_type(4))) float f32x4;
typedef __attribute__((ext_vector_type(4))) u16 u16x4;

#define DEVFN static __device__ __forceinline__

static constexpr int LQ = 1024, NN = 8, EE = 1024, HH = 8, SS = 1024;
static constexpr long LNE = (long)LQ * NN * EE;   // 8,388,608
static constexpr long MM = 1048576;               // 1024*1024

// ws offsets (u16 units unless noted)
static constexpr long OF_QBF   = 0;
static constexpr long OF_KBF   = 8388608;
static constexpr long OF_VALT  = 16777216;
static constexpr long OF_F     = 25165824;   // WqT first, then F overwrites
static constexpr long OF_WKT   = 33554432;
static constexpr long OF_WVT   = 41943040;
static constexpr long OF_WOT   = 50331648;
static constexpr long OF_WOUTB = 58720256;
static constexpr long OF_GT    = 67108864;
static constexpr long OF_BM    = 75497472;
static constexpr long OF_T     = 83886080;   // 67,108,864 u16; becomes P after scores
static constexpr long OF_U     = 150994944;  // 67,108,864 u16
static constexpr long OF_PART_F  = 109051904; // float index: 2 x 8,388,608 f32
static constexpr long OF_SMALL_F = 125829120; // float index

DEVFN u16 f2bf(float x) {
  u32 u = __builtin_bit_cast(u32, x);
  u = (u + 0x7FFFu + ((u >> 16) & 1u)) >> 16;
  return (u16)u;
}
DEVFN float bf2f(u16 x) { return __builtin_bit_cast(float, (u32)x << 16); }

DEVFN void gload16(const u16* g, u16* l) {
  __builtin_amdgcn_global_load_lds(
      (const __attribute__((address_space(1))) void*)(uintptr_t)g,
      (__attribute__((address_space(3))) void*)(uintptr_t)l, 16, 0, 0);
}

// ---------------- plain converts: query, key, Wout (each 8,388,608 elems) ---
struct Cvt3P { const float* s[3]; u16* d[3]; };
__global__ __launch_bounds__(256) void k_cvt3(Cvt3P p) {
  const int z = blockIdx.y;
  const float* s = p.s[z];
  u16* d = p.d[z];
  long i = (long)blockIdx.x * 256 + threadIdx.x;  // 512 blocks, 16 iters
  for (; i < 2097152; i += 131072) {
    float4 v = reinterpret_cast<const float4*>(s)[i];
    u16x4 o;
    o.x = f2bf(v.x); o.y = f2bf(v.y); o.z = f2bf(v.z); o.w = f2bf(v.w);
    reinterpret_cast<u16x4*>(d)[i] = o;
  }
}

// ---------------- 5-way transpose-convert (1024x1024 blocks, 8 z each) ------
struct Tp5P { const float* s[5]; u16* d[5]; int sld[5]; long szs[5]; long dzs[5]; };
__global__ __launch_bounds__(256) void k_tp5(Tp5P p) {
  const int cfg = blockIdx.z >> 3, zz = blockIdx.z & 7;
  const float* src = p.s[cfg] + (long)zz * p.szs[cfg];
  u16* dst = p.d[cfg] + (long)zz * p.dzs[cfg];
  const int sld = p.sld[cfg];
  __shared__ float t[64][65];
  const int r = threadIdx.x >> 4, c4 = (threadIdx.x & 15) * 4;
#pragma unroll
  for (int rr = 0; rr < 64; rr += 16) {
    float4 v = *reinterpret_cast<const float4*>(
        &src[(long)(blockIdx.y * 64 + r + rr) * sld + blockIdx.x * 64 + c4]);
    t[r + rr][c4] = v.x; t[r + rr][c4 + 1] = v.y;
    t[r + rr][c4 + 2] = v.z; t[r + rr][c4 + 3] = v.w;
  }
  __syncthreads();
#pragma unroll
  for (int rr = 0; rr < 64; rr += 16) {
    u16x4 o;
    o.x = f2bf(t[c4][r + rr]);     o.y = f2bf(t[c4 + 1][r + rr]);
    o.z = f2bf(t[c4 + 2][r + rr]); o.w = f2bf(t[c4 + 3][r + rr]);
    *reinterpret_cast<u16x4*>(
        &dst[(long)(blockIdx.x * 64 + r + rr) * 1024 + blockIdx.y * 64 + c4]) = o;
  }
}

// ---------------- c[h] = bq_h · bk_h ----------------------------------------
__global__ __launch_bounds__(256) void k_c(const float* __restrict__ bqkv,
                                           float* __restrict__ c) {
  const int h = blockIdx.x, t = threadIdx.x;
  float s = 0.f;
  for (int i = t; i < 1024; i += 256)
    s += bqkv[h * 3072 + i] * bqkv[h * 3072 + 1024 + i];
#pragma unroll
  for (int o = 1; o < 64; o <<= 1) s += __shfl_xor(s, o);
  __shared__ float ps[4];
  if ((t & 63) == 0) ps[t >> 6] = s;
  __syncthreads();
  if (t == 0) c[h] = ps[0] + ps[1] + ps[2] + ps[3];
}

// ---------------- a_h[e]=Σ_d Wq[d,e]bk[d]; b_h[e]=Σ_d Wk[d,e]bq[d] (partial) -
__global__ __launch_bounds__(256) void k_ab(const float* __restrict__ Wqkv,
                                            const float* __restrict__ bqkv,
                                            float* __restrict__ ap,
                                            float* __restrict__ bp) {
  const int ec = blockIdx.x, h = blockIdx.y, dc = blockIdx.z, t = threadIdx.x;
  const int e = ec * 256 + t;
  const float* wq = Wqkv + (long)h * 3145728;
  const float* wk = wq + 1048576;
  const float* bq = bqkv + h * 3072;
  const float* bk = bq + 1024;
  float sa = 0.f, sb = 0.f;
  for (int dd = 0; dd < 128; ++dd) {
    const int d = dc * 128 + dd;
    sa += wq[(long)d * 1024 + e] * bk[d];
    sb += wk[(long)d * 1024 + e] * bq[d];
  }
  ap[dc * 8192 + h * 1024 + e] = sa;
  bp[dc * 8192 + h * 1024 + e] = sb;
}

__global__ __launch_bounds__(256) void k_red(const float* __restrict__ ap,
                                             const float* __restrict__ bp,
                                             float* __restrict__ a,
                                             float* __restrict__ b) {
  const int i = blockIdx.x * 256 + threadIdx.x;  // 8192
  float sa = 0.f, sb = 0.f;
#pragma unroll
  for (int dc = 0; dc < 8; ++dc) { sa += ap[dc * 8192 + i]; sb += bp[dc * 8192 + i]; }
  a[i] = sa; b[i] = sb;
}

// ---------------- alpha[h,n,l] = query_row·a_h (+c_h); beta likewise --------
__global__ __launch_bounds__(256) void k_rowdot(const float* __restrict__ X,
                                                const float* __restrict__ V,
                                                const float* __restrict__ c,
                                                float* __restrict__ OUT,
                                                int addc) {
  const int wave = threadIdx.x >> 6, lane = threadIdx.x & 63;
  const int r = blockIdx.x * 4 + wave;  // row (l*8+n) or (s*8+n)
  const float4* xr = reinterpret_cast<const float4*>(X + (long)r * 1024);
  float acc[8];
#pragma unroll
  for (int h = 0; h < 8; ++h) acc[h] = 0.f;
#pragma unroll
  for (int it = 0; it < 4; ++it) {
    float4 q = xr[it * 64 + lane];
#pragma unroll
    for (int h = 0; h < 8; ++h) {
      float4 av = reinterpret_cast<const float4*>(V + h * 1024)[it * 64 + lane];
      acc[h] += q.x * av.x + q.y * av.y + q.z * av.z + q.w * av.w;
    }
  }
#pragma unroll
  for (int h = 0; h < 8; ++h)
#pragma unroll
    for (int o = 1; o < 64; o <<= 1) acc[h] += __shfl_xor(acc[h], o);
  if (lane == 0) {
    const int idx = r >> 3, n = r & 7;
#pragma unroll
    for (int h = 0; h < 8; ++h)
      OUT[h * 8192 + n * 1024 + idx] = acc[h] + (addc ? c[h] : 0.f);
  }
}

// ---------------- be2[e] = bout + Σ Wout[e,:]·bo_flat + Σ Bm[e,:]·bv --------
__global__ __launch_bounds__(256) void k_be2(const float* __restrict__ Wout,
                                             const float* __restrict__ bo,
                                             const float* __restrict__ bout,
                                             const float* __restrict__ bqkv,
                                             const u16* __restrict__ Bm,
                                             float* __restrict__ be2) {
  const int e = blockIdx.x, t = threadIdx.x;
  float s = 0.f;
  for (int i = t; i < 8192; i += 256) {
    s += Wout[(long)e * 8192 + i] * bo[i];
    const int h = i >> 10, d = i & 1023;
    s += bf2f(Bm[(long)e * 8192 + i]) * bqkv[h * 3072 + 2048 + d];
  }
#pragma unroll
  for (int o = 1; o < 64; o <<= 1) s += __shfl_xor(s, o);
  __shared__ float ps[4];
  if ((t & 63) == 0) ps[t >> 6] = s;
  __syncthreads();
  if (t == 0) be2[e] = bout[e] + ps[0] + ps[1] + ps[2] + ps[3];
}

// ---------------- out = p0 + p1 + be2 ---------------------------------------
__global__ __launch_bounds__(256) void k_combine(const float* __restrict__ p0,
                                                 const float* __restrict__ p1,
                                                 const float* __restrict__ be,
                                                 float* __restrict__ out) {
  long i = (long)blockIdx.x * 256 + threadIdx.x;
  const long st = (long)gridDim.x * 256;
  for (; i < 2097152; i += st) {
    float4 a = reinterpret_cast<const float4*>(p0)[i];
    float4 b = reinterpret_cast<const float4*>(p1)[i];
    float4 c = reinterpret_cast<const float4*>(be)[i & 255];
    float4 o = {a.x + b.x + c.x, a.y + b.y + c.y, a.z + b.z + c.z, a.w + b.w + c.w};
    reinterpret_cast<float4*>(out)[i] = o;
  }
}

// ---------------- softmax rows of 1024, in-place f32 + bf16 P ---------------
__global__ __launch_bounds__(256) void k_softmax(float* __restrict__ S,
                                                 u16* __restrict__ P) {
  __shared__ float smax[4], ssum[4];
  const long row = blockIdx.x;
  float* sr = S + row * 1024;
  const int tid = threadIdx.x;
  float4 v = reinterpret_cast<const float4*>(sr)[tid];
  float m = fmaxf(fmaxf(v.x, v.y), fmaxf(v.z, v.w));
#pragma unroll
  for (int o = 1; o < 64; o <<= 1) m = fmaxf(m, __shfl_xor(m, o));
  const int wv = tid >> 6, ln = tid & 63;
  if (ln == 0) smax[wv] = m;
  __syncthreads();
  m = fmaxf(fmaxf(smax[0], smax[1]), fmaxf(smax[2], smax[3]));
  v.x = __expf(v.x - m); v.y = __expf(v.y - m);
  v.z = __expf(v.z - m); v.w = __expf(v.w - m);
  float s = v.x + v.y + v.z + v.w;
#pragma unroll
  for (int o = 1; o < 64; o <<= 1) s += __shfl_xor(s, o);
  if (ln == 0) ssum[wv] = s;
  __syncthreads();
  s = ssum[0] + ssum[1] + ssum[2] + ssum[3];
  const float inv = 1.0f / s;
  v.x *= inv; v.y *= inv; v.z *= inv; v.w *= inv;
  reinterpret_cast<float4*>(sr)[tid] = v;
  u16x4 o4;
  o4.x = f2bf(v.x); o4.y = f2bf(v.y); o4.z = f2bf(v.z); o4.w = f2bf(v.w);
  reinterpret_cast<u16x4*>(P + row * 1024)[tid] = o4;
}

// ---------------- 256x256 8-phase batched B^T GEMM --------------------------
struct GemmP {
  const u16* A; const u16* B;
  const float* bR; const float* bC;
  float* Cf; u16* Cb;
  int lda, ldb, ldc, K, NB;
  long sAh, sAn, sBh, sBn, sCh, sCn;
  long bRh, bRn, bCh, bCn;
  float scale;
};
struct GemmP2 { GemmP p0, p1; int split; };

template <int M0, int N0>
DEVFN void quad(f32x4 (&acc)[8][4], bf16x8 (&a)[4][2], bf16x8 (&b)[4][2]) {
#pragma unroll
  for (int mi = 0; mi < 4; ++mi)
#pragma unroll
    for (int ni = 0; ni < 2; ++ni) {
      acc[M0 + mi][N0 + ni] = __builtin_amdgcn_mfma_f32_16x16x32_bf16(
          a[mi][0], b[N0 + ni][0], acc[M0 + mi][N0 + ni], 0, 0, 0);
      acc[M0 + mi][N0 + ni] = __builtin_amdgcn_mfma_f32_16x16x32_bf16(
          a[mi][1], b[N0 + ni][1], acc[M0 + mi][N0 + ni], 0, 0, 0);
    }
}

#define BAR() asm volatile("s_barrier" ::: "memory")
#define VMCNT2() asm volatile("s_waitcnt vmcnt(2)" ::: "memory")
#define VMCNT0() asm volatile("s_waitcnt vmcnt(0)" ::: "memory")
#define SB0() __builtin_amdgcn_sched_barrier(0)

DEVFN void swz_block(int& bx, int& by, int& bz) {
  long lid = blockIdx.x + (long)gridDim.x * (blockIdx.y + (long)gridDim.y * blockIdx.z);
  const long nwg = (long)gridDim.x * gridDim.y * gridDim.z;
  long s = (nwg % 8 == 0) ? ((lid % 8) * (nwg / 8) + lid / 8) : lid;
  bx = (int)(s % gridDim.x);
  long r2 = s / gridDim.x;
  by = (int)(r2 % gridDim.y);
  bz = (int)(r2 / gridDim.y);
}

template <int HAS_BR, int HAS_BC, int OUT_F32>
DEVFN void gemm_body(const GemmP& p, int bx, int by, int bz) {
  const int h = bz / p.NB, n = bz % p.NB;
  const u16* Ab = p.A + (long)h * p.sAh + (long)n * p.sAn;
  const u16* Bb = p.B + (long)h * p.sBh + (long)n * p.sBn;
  const long coff = (long)h * p.sCh + (long)n * p.sCn;
  const int row0 = by * 256;
  const int col0 = bx * 256;

  __shared__ u16 LDSU[65536];  // 128 KiB

  const int tid = threadIdx.x;
  const int wave = tid >> 6, lane = tid & 63;
  const int wr = wave >> 2, wc = wave & 3;
  const int NT = p.K >> 6;

  f32x4 acc[8][4];
  const f32x4 zero = {0.f, 0.f, 0.f, 0.f};
#pragma unroll
  for (int i = 0; i < 8; ++i)
#pragma unroll
    for (int j = 0; j < 4; ++j) acc[i][j] = zero;

  const int swc = ((lane & 7) ^ ((lane >> 3) & 7)) * 8;
  const u16* Ag = Ab + (long)(row0 + wave * 16 + (lane >> 3)) * p.lda + swc;
  const u16* Bg = Bb + (long)(col0 + wave * 16 + (lane >> 3)) * p.ldb + swc;

  auto STAGE = [&](int hh) {
    const int kt = hh >> 2;
    if (kt < NT) {
      const int pt = hh & 3;  // 0:A0 1:B0 2:A1 3:B1
      const int hf = pt >> 1;
      u16* l = &LDSU[((pt & 1) ? 32768 : 0) + (kt & 1) * 16384 + hf * 8192 + wave * 1024];
      const int ld = (pt & 1) ? p.ldb : p.lda;
      const u16* g = ((pt & 1) ? Bg : Ag) + (long)hf * 128 * ld + kt * 64;
      gload16(g, l);
      gload16(g + 8L * ld, l + 512);
    }
  };

  STAGE(0); STAGE(1); STAGE(2); STAGE(3); STAGE(4);
  VMCNT2();
  BAR();

  const int rA = lane & 15;
  const int c0 = (((lane >> 4)) ^ (lane & 7)) * 8;
  const int c1 = ((4 + (lane >> 4)) ^ (lane & 7)) * 8;

  bf16x8 a[4][2], b[4][2];

  for (int t = 0; t < NT; ++t) {
    const int db = (t & 1) * 16384;
    const u16* Ar = &LDSU[db + wr * 8192 + rA * 64];
    const u16* Br = &LDSU[32768 + db + (wc >> 1) * 8192 + ((wc & 1) * 64 + rA) * 64];

#pragma unroll
    for (int mi = 0; mi < 4; ++mi) {
      a[mi][0] = *reinterpret_cast<const bf16x8*>(&Ar[mi * 1024 + c0]);
      a[mi][1] = *reinterpret_cast<const bf16x8*>(&Ar[mi * 1024 + c1]);
    }
#pragma unroll
    for (int ni = 0; ni < 2; ++ni) {
      b[ni][0] = *reinterpret_cast<const bf16x8*>(&Br[ni * 1024 + c0]);
      b[ni][1] = *reinterpret_cast<const bf16x8*>(&Br[ni * 1024 + c1]);
    }
    STAGE(4 * t + 5);
    BAR();
    SB0(); __builtin_amdgcn_s_setprio(1);
    quad<0, 0>(acc, a, b);
    __builtin_amdgcn_s_setprio(0); SB0();
    BAR();

#pragma unroll
    for (int ni = 2; ni < 4; ++ni) {
      b[ni][0] = *reinterpret_cast<const bf16x8*>(&Br[ni * 1024 + c0]);
      b[ni][1] = *reinterpret_cast<const bf16x8*>(&Br[ni * 1024 + c1]);
    }
    STAGE(4 * t + 6);
    BAR();
    SB0(); __builtin_amdgcn_s_setprio(1);
    quad<0, 2>(acc, a, b);
    __builtin_amdgcn_s_setprio(0); SB0();
    BAR();

#pragma unroll
    for (int mi = 0; mi < 4; ++mi) {
      a[mi][0] = *reinterpret_cast<const bf16x8*>(&Ar[(4 + mi) * 1024 + c0]);
      a[mi][1] = *reinterpret_cast<const bf16x8*>(&Ar[(4 + mi) * 1024 + c1]);
    }
    STAGE(4 * t + 7);
    BAR();
    SB0(); __builtin_amdgcn_s_setprio(1);
    quad<4, 0>(acc, a, b);
    __builtin_amdgcn_s_setprio(0); SB0();
    BAR();

    STAGE(4 * t + 8);
    if (t < NT - 2) { VMCNT2(); }
    else if (t == NT - 2) { VMCNT0(); }
    BAR();
    SB0(); __builtin_amdgcn_s_setprio(1);
    quad<4, 2>(acc, a, b);
    __builtin_amdgcn_s_setprio(0); SB0();
    BAR();
  }

  const int crow = (lane >> 4) * 4;
  const int ccol = lane & 15;
#pragma unroll
  for (int mi = 0; mi < 8; ++mi) {
#pragma unroll
    for (int j = 0; j < 4; ++j) {
      const int grow = row0 + wr * 128 + mi * 16 + crow + j;
#pragma unroll
      for (int ni = 0; ni < 4; ++ni) {
        const int gcol = col0 + wc * 64 + ni * 16 + ccol;
        float v = acc[mi][ni][j];
        if constexpr (HAS_BR) v += p.bR[(long)h * p.bRh + (long)n * p.bRn + grow];
        if constexpr (HAS_BC) v += p.bC[(long)h * p.bCh + (long)n * p.bCn + gcol];
        v *= p.scale;
        if constexpr (OUT_F32)
          p.Cf[coff + (long)grow * p.ldc + gcol] = v;
        else
          p.Cb[coff + (long)grow * p.ldc + gcol] = f2bf(v);
      }
    }
  }
}

template <int HAS_BR, int HAS_BC, int OUT_F32>
__global__ __launch_bounds__(512, 2) void k_gemm256(GemmP p) {
  int bx, by, bz;
  swz_block(bx, by, bz);
  gemm_body<HAS_BR, HAS_BC, OUT_F32>(p, bx, by, bz);
}

template <int HAS_BR, int HAS_BC, int OUT_F32>
__global__ __launch_bounds__(512, 2) void k_gemm256_pair(GemmP2 pp) {
  int bx, by, bz;
  swz_block(bx, by, bz);
  if (bz < pp.split)
    gemm_body<HAS_BR, HAS_BC, OUT_F32>(pp.p0, bx, by, bz);
  else
    gemm_body<HAS_BR, HAS_BC, OUT_F32>(pp.p1, bx, by, bz - pp.split);
}

// ============================================================================
extern "C" void kernel_launch(void* const* d_in, const int* in_sizes, int n_in,
                              void* d_out, int out_size, void* d_ws,
                              size_t ws_size, hipStream_t stream) {
  const float* query = (const float*)d_in[0];
  const float* key_  = (const float*)d_in[1];
  const float* value = (const float*)d_in[2];
  const float* Wqkv  = (const float*)d_in[3];
  const float* bqkv  = (const float*)d_in[4];
  const float* Wo    = (const float*)d_in[5];
  const float* bo    = (const float*)d_in[6];
  const float* Wout  = (const float*)d_in[7];
  const float* bout  = (const float*)d_in[8];

  float* out  = (float*)d_out;
  float* attn = out + LNE;  // (H,N,L,S) f32

  u16* ws = (u16*)d_ws;
  u16* qbf   = ws + OF_QBF;
  u16* kbf   = ws + OF_KBF;
  u16* valT  = ws + OF_VALT;
  u16* WqT_F = ws + OF_F;      // WqT, later F
  u16* WkT   = ws + OF_WKT;
  u16* WvT   = ws + OF_WVT;
  u16* WoT   = ws + OF_WOT;
  u16* Woutb = ws + OF_WOUTB;
  u16* Gt    = ws + OF_GT;
  u16* Bm    = ws + OF_BM;
  u16* Tbuf  = ws + OF_T;      // later P
  u16* Ubuf  = ws + OF_U;
  float* part = (float*)d_ws + OF_PART_F;
  float* S    = (float*)d_ws + OF_SMALL_F;
  float* av    = S;              // 8192
  float* bv2   = S + 8192;       // 8192
  float* cc    = S + 16384;      // 16
  float* alpha = S + 16400;      // 65536
  float* beta  = S + 81936;      // 65536
  float* be2   = S + 147472;     // 1024
  float* apart = S + 148496;     // 65536
  float* bpart = S + 214032;     // 65536

  // ---- converts ----
  {
    Cvt3P p;
    p.s[0] = query; p.s[1] = key_; p.s[2] = Wout;
    p.d[0] = qbf;   p.d[1] = kbf;  p.d[2] = Woutb;
    k_cvt3<<<dim3(512, 3), 256, 0, stream>>>(p);
  }
  {
    Tp5P p;
    p.s[0] = Wqkv;           p.d[0] = WqT_F; p.sld[0] = 1024; p.szs[0] = 3145728; p.dzs[0] = MM;
    p.s[1] = Wqkv + 1048576; p.d[1] = WkT;   p.sld[1] = 1024; p.szs[1] = 3145728; p.dzs[1] = MM;
    p.s[2] = Wqkv + 2097152; p.d[2] = WvT;   p.sld[2] = 1024; p.szs[2] = 3145728; p.dzs[2] = MM;
    p.s[3] = Wo;             p.d[3] = WoT;   p.sld[3] = 1024; p.szs[3] = MM;      p.dzs[3] = MM;
    p.s[4] = value;          p.d[4] = valT;  p.sld[4] = 8192; p.szs[4] = 1024;    p.dzs[4] = MM;
    k_tp5<<<dim3(16, 16, 40), 256, 0, stream>>>(p);
  }
  // ---- bias precomputes ----
  k_c<<<8, 256, 0, stream>>>(bqkv, cc);
  k_ab<<<dim3(4, 8, 8), 256, 0, stream>>>(Wqkv, bqkv, apart, bpart);
  k_red<<<32, 256, 0, stream>>>(apart, bpart, av, bv2);
  k_rowdot<<<2048, 256, 0, stream>>>(query, av, cc, alpha, 1);
  k_rowdot<<<2048, 256, 0, stream>>>(key_, bv2, cc, beta, 0);

  const dim3 blk(512);

  // ---- Gt = WkT·WqT^T  and  Bm = Woutb·WoT^T  (one paired dispatch) ----
  {
    GemmP g = {};
    g.A = WkT; g.lda = 1024; g.sAh = MM; g.sAn = 0;
    g.B = WqT_F; g.ldb = 1024; g.sBh = MM; g.sBn = 0;
    g.Cb = Gt; g.ldc = 1024; g.sCh = MM; g.sCn = 0;
    g.K = 1024; g.NB = 1; g.scale = 1.f;
    GemmP m = {};
    m.A = Woutb; m.lda = 8192; m.sAh = 1024; m.sAn = 0;
    m.B = WoT; m.ldb = 1024; m.sBh = MM; m.sBn = 0;
    m.Cb = Bm; m.ldc = 8192; m.sCh = 1024; m.sCn = 0;
    m.K = 1024; m.NB = 1; m.scale = 1.f;
    GemmP2 pp = {g, m, 8};
    k_gemm256_pair<0, 0, 0><<<dim3(4, 4, 16), blk, 0, stream>>>(pp);
  }
  // ---- be2 (needs Bm) ----
  k_be2<<<1024, 256, 0, stream>>>(Wout, bo, bout, bqkv, Bm, be2);
  // ---- T = query·Gt^T (z<64)  and  F = Bm·WvT^T (z>=64) ----
  {
    GemmP t = {};
    t.A = qbf; t.lda = 8192; t.sAh = 0; t.sAn = 1024;
    t.B = Gt; t.ldb = 1024; t.sBh = MM; t.sBn = 0;
    t.Cb = Tbuf; t.ldc = 8192; t.sCh = 8388608; t.sCn = 1024;
    t.K = 1024; t.NB = 8; t.scale = 1.f;
    GemmP f = {};
    f.A = Bm; f.lda = 8192; f.sAh = 1024; f.sAn = 0;
    f.B = WvT; f.ldb = 1024; f.sBh = MM; f.sBn = 0;
    f.Cb = WqT_F; f.ldc = 8192; f.sCh = 1024; f.sCn = 0;
    f.K = 1024; f.NB = 1; f.scale = 1.f;
    GemmP2 pp = {t, f, 64};
    k_gemm256_pair<0, 0, 0><<<dim3(4, 4, 72), blk, 0, stream>>>(pp);
  }
  // ---- scores: attn[h,n,l,s] = (T·key^T + alpha + beta) / 32 ----
  {
    GemmP p = {};
    p.A = Tbuf; p.lda = 8192; p.sAh = 8388608; p.sAn = 1024;
    p.B = kbf; p.ldb = 8192; p.sBh = 0; p.sBn = 1024;
    p.Cf = attn; p.ldc = 1024; p.sCh = 8388608; p.sCn = 1048576;
    p.bR = alpha; p.bRh = 8192; p.bRn = 1024;
    p.bC = beta;  p.bCh = 8192; p.bCn = 1024;
    p.K = 1024; p.NB = 8; p.scale = 1.f / 32.f;
    k_gemm256<1, 1, 1><<<dim3(4, 4, 64), blk, 0, stream>>>(p);
  }
  // ---- softmax (P into Tbuf slot; T is dead) ----
  k_softmax<<<HH * NN * LQ, 256, 0, stream>>>(attn, Tbuf);
  // ---- U = P·value^T: U[(l,n)][(h,ev)] ----
  {
    GemmP p = {};
    p.A = Tbuf; p.lda = 1024; p.sAh = 8388608; p.sAn = 1048576;
    p.B = valT; p.ldb = 1024; p.sBh = 0; p.sBn = 1048576;
    p.Cb = Ubuf; p.ldc = 65536; p.sCh = 1024; p.sCn = 8192;
    p.K = 1024; p.NB = 8; p.scale = 1.f;
    k_gemm256<0, 0, 0><<<dim3(4, 4, 64), blk, 0, stream>>>(p);
  }
  // ---- out partials: part[z] = U·F^T over K-half z ----
  {
    GemmP p = {};
    p.A = Ubuf; p.lda = 8192; p.sAh = 4096; p.sAn = 0;
    p.B = WqT_F; p.ldb = 8192; p.sBh = 4096; p.sBn = 0;
    p.Cf = part; p.ldc = 1024; p.sCh = 8388608; p.sCn = 0;
    p.K = 4096; p.NB = 1; p.scale = 1.f;
    k_gemm256<0, 0, 1><<<dim3(4, 32, 2), blk, 0, stream>>>(p);
  }
  // ---- combine ----
  k_combine<<<2048, 256, 0, stream>>>(part, part + 8388608, be2, out);
}

// Round 4
// 991.597 us; speedup vs baseline: 1.8698x; 1.0120x over previous
//
#include <hip/hip_runtime.h>
#include <stdint.h>

// ============================================================================
// CrossMultiHeadAttention (L=1024, N=8, E=1024, H=8) — round 4.
//
//  scores+softmax FUSED (k_fsc): per block 64 l-rows x full 1024 s in regs;
//    attn = softmax((T·key^T + beta)/32)  [alpha & c are row-constant -> cancel]
//    writes normalized attn f32 + P bf16 directly (no raw-score round trip).
//  out = sum_h (P·value)_h · F_h^T + be2,  F = (Wout·Wo)·Wv ; final GEMM split-K=4.
// ============================================================================

typedef unsigned short u16;
typedef unsigned int u32;
typedef __attribute__((ext_vector_type(8))) __bf16 bf16x8;
typedef __attribute__((ext_vector_type(4))) float f32x4;
typedef __attribute__((ext_vector_type(4))) u16 u16x4;

#define DEVFN static __device__ __forceinline__

static constexpr int LQ = 1024, NN = 8, EE = 1024, HH = 8, SS = 1024;
static constexpr long LNE = (long)LQ * NN * EE;   // 8,388,608
static constexpr long MM = 1048576;

// ws offsets (u16 elems)
static constexpr long OF_QBF   = 0;
static constexpr long OF_KBF   = 8388608;
static constexpr long OF_VALT  = 16777216;
static constexpr long OF_F     = 25165824;   // WqT first, later F
static constexpr long OF_WKT   = 33554432;
static constexpr long OF_WVT   = 41943040;
static constexpr long OF_WOT   = 50331648;
static constexpr long OF_WOUTB = 58720256;
static constexpr long OF_GT    = 67108864;
static constexpr long OF_BM    = 75497472;
static constexpr long OF_T     = 83886080;   // 67M u16: T, later U
static constexpr long OF_P     = 150994944;  // 67M u16: P, later 4 f32 partials
static constexpr long OF_SMALL_F = 109051904; // float index (== u16 218103808)

DEVFN u16 f2bf(float x) {
  u32 u = __builtin_bit_cast(u32, x);
  u = (u + 0x7FFFu + ((u >> 16) & 1u)) >> 16;
  return (u16)u;
}
DEVFN float bf2f(u16 x) { return __builtin_bit_cast(float, (u32)x << 16); }

DEVFN void gload16(const u16* g, u16* l) {
  __builtin_amdgcn_global_load_lds(
      (const __attribute__((address_space(1))) void*)(uintptr_t)g,
      (__attribute__((address_space(3))) void*)(uintptr_t)l, 16, 0, 0);
}

#define BAR() asm volatile("s_barrier" ::: "memory")
#define VMCNT2() asm volatile("s_waitcnt vmcnt(2)" ::: "memory")
#define VMCNT0() asm volatile("s_waitcnt vmcnt(0)" ::: "memory")
#define VMCNT8() asm volatile("s_waitcnt vmcnt(8)" ::: "memory")
#define VMCNT9() asm volatile("s_waitcnt vmcnt(9)" ::: "memory")
#define SB0() __builtin_amdgcn_sched_barrier(0)

// ---------------- converts ----------------
struct Cvt3P { const float* s[3]; u16* d[3]; };
__global__ __launch_bounds__(256) void k_cvt3(Cvt3P p) {
  const int z = blockIdx.y;
  const float* s = p.s[z];
  u16* d = p.d[z];
  long i = (long)blockIdx.x * 256 + threadIdx.x;
  for (; i < 2097152; i += 131072) {
    float4 v = reinterpret_cast<const float4*>(s)[i];
    u16x4 o;
    o.x = f2bf(v.x); o.y = f2bf(v.y); o.z = f2bf(v.z); o.w = f2bf(v.w);
    reinterpret_cast<u16x4*>(d)[i] = o;
  }
}

struct Tp5P { const float* s[5]; u16* d[5]; int sld[5]; long szs[5]; long dzs[5]; };
__global__ __launch_bounds__(256) void k_tp5(Tp5P p) {
  const int cfg = blockIdx.z >> 3, zz = blockIdx.z & 7;
  const float* src = p.s[cfg] + (long)zz * p.szs[cfg];
  u16* dst = p.d[cfg] + (long)zz * p.dzs[cfg];
  const int sld = p.sld[cfg];
  __shared__ float t[64][65];
  const int r = threadIdx.x >> 4, c4 = (threadIdx.x & 15) * 4;
#pragma unroll
  for (int rr = 0; rr < 64; rr += 16) {
    float4 v = *reinterpret_cast<const float4*>(
        &src[(long)(blockIdx.y * 64 + r + rr) * sld + blockIdx.x * 64 + c4]);
    t[r + rr][c4] = v.x; t[r + rr][c4 + 1] = v.y;
    t[r + rr][c4 + 2] = v.z; t[r + rr][c4 + 3] = v.w;
  }
  __syncthreads();
#pragma unroll
  for (int rr = 0; rr < 64; rr += 16) {
    u16x4 o;
    o.x = f2bf(t[c4][r + rr]);     o.y = f2bf(t[c4 + 1][r + rr]);
    o.z = f2bf(t[c4 + 2][r + rr]); o.w = f2bf(t[c4 + 3][r + rr]);
    *reinterpret_cast<u16x4*>(
        &dst[(long)(blockIdx.x * 64 + r + rr) * 1024 + blockIdx.y * 64 + c4]) = o;
  }
}

// ---------------- beta vector: bvec_h[e] = sum_d Wk[h][d][e]*bq[h][d] -------
__global__ __launch_bounds__(256) void k_bvec(const float* __restrict__ Wqkv,
                                              const float* __restrict__ bqkv,
                                              float* __restrict__ bp) {
  const int ec = blockIdx.x, h = blockIdx.y, dc = blockIdx.z, t = threadIdx.x;
  const int e = ec * 256 + t;
  const float* wk = Wqkv + (long)h * 3145728 + 1048576;
  const float* bq = bqkv + h * 3072;
  float sb = 0.f;
  for (int dd = 0; dd < 128; ++dd) {
    const int d = dc * 128 + dd;
    sb += wk[(long)d * 1024 + e] * bq[d];
  }
  bp[dc * 8192 + h * 1024 + e] = sb;
}
__global__ __launch_bounds__(256) void k_redb(const float* __restrict__ bp,
                                              float* __restrict__ b) {
  const int i = blockIdx.x * 256 + threadIdx.x;
  float sb = 0.f;
#pragma unroll
  for (int dc = 0; dc < 8; ++dc) sb += bp[dc * 8192 + i];
  b[i] = sb;
}

// ---------------- beta[h,n,s] = key_row(s,n) · bvec_h -----------------------
__global__ __launch_bounds__(256) void k_rowdot(const float* __restrict__ X,
                                                const float* __restrict__ V,
                                                float* __restrict__ OUT) {
  const int wave = threadIdx.x >> 6, lane = threadIdx.x & 63;
  const int r = blockIdx.x * 4 + wave;  // row (s*8+n)
  const float4* xr = reinterpret_cast<const float4*>(X + (long)r * 1024);
  float acc[8];
#pragma unroll
  for (int h = 0; h < 8; ++h) acc[h] = 0.f;
#pragma unroll
  for (int it = 0; it < 4; ++it) {
    float4 q = xr[it * 64 + lane];
#pragma unroll
    for (int h = 0; h < 8; ++h) {
      float4 av = reinterpret_cast<const float4*>(V + h * 1024)[it * 64 + lane];
      acc[h] += q.x * av.x + q.y * av.y + q.z * av.z + q.w * av.w;
    }
  }
#pragma unroll
  for (int h = 0; h < 8; ++h)
#pragma unroll
    for (int o = 1; o < 64; o <<= 1) acc[h] += __shfl_xor(acc[h], o);
  if (lane == 0) {
    const int idx = r >> 3, n = r & 7;
#pragma unroll
    for (int h = 0; h < 8; ++h) OUT[h * 8192 + n * 1024 + idx] = acc[h];
  }
}

// ---------------- be2[e] = bout + Wout[e,:]·bo + Bm[e,:]·bv -----------------
__global__ __launch_bounds__(256) void k_be2(const float* __restrict__ Wout,
                                             const float* __restrict__ bo,
                                             const float* __restrict__ bout,
                                             const float* __restrict__ bqkv,
                                             const u16* __restrict__ Bm,
                                             float* __restrict__ be2) {
  const int e = blockIdx.x, t = threadIdx.x;
  float s = 0.f;
  for (int i = t; i < 8192; i += 256) {
    s += Wout[(long)e * 8192 + i] * bo[i];
    const int h = i >> 10, d = i & 1023;
    s += bf2f(Bm[(long)e * 8192 + i]) * bqkv[h * 3072 + 2048 + d];
  }
#pragma unroll
  for (int o = 1; o < 64; o <<= 1) s += __shfl_xor(s, o);
  __shared__ float ps[4];
  if ((t & 63) == 0) ps[t >> 6] = s;
  __syncthreads();
  if (t == 0) be2[e] = bout[e] + ps[0] + ps[1] + ps[2] + ps[3];
}

// ---------------- out = p0+p1+p2+p3 + be2 -----------------------------------
__global__ __launch_bounds__(256) void k_combine4(const float* __restrict__ pt,
                                                  const float* __restrict__ be,
                                                  float* __restrict__ out) {
  long i = (long)blockIdx.x * 256 + threadIdx.x;
  const long st = (long)gridDim.x * 256;
  for (; i < 2097152; i += st) {
    float4 a = reinterpret_cast<const float4*>(pt)[i];
    float4 b = reinterpret_cast<const float4*>(pt + 8388608)[i];
    float4 cc = reinterpret_cast<const float4*>(pt + 16777216)[i];
    float4 d = reinterpret_cast<const float4*>(pt + 25165824)[i];
    float4 e = reinterpret_cast<const float4*>(be)[i & 255];
    float4 o = {a.x + b.x + cc.x + d.x + e.x, a.y + b.y + cc.y + d.y + e.y,
                a.z + b.z + cc.z + d.z + e.z, a.w + b.w + cc.w + d.w + e.w};
    reinterpret_cast<float4*>(out)[i] = o;
  }
}

// ---------------- generic 256x256 8-phase B^T GEMM --------------------------
struct GemmP {
  const u16* A; const u16* B;
  float* Cf; u16* Cb;
  int lda, ldb, ldc, K, NB;
  long sAh, sAn, sBh, sBn, sCh, sCn;
  float scale;
};
struct GemmP2 { GemmP p0, p1; int split; };

template <int M0, int N0>
DEVFN void quad(f32x4 (&acc)[8][4], bf16x8 (&a)[4][2], bf16x8 (&b)[4][2]) {
#pragma unroll
  for (int mi = 0; mi < 4; ++mi)
#pragma unroll
    for (int ni = 0; ni < 2; ++ni) {
      acc[M0 + mi][N0 + ni] = __builtin_amdgcn_mfma_f32_16x16x32_bf16(
          a[mi][0], b[N0 + ni][0], acc[M0 + mi][N0 + ni], 0, 0, 0);
      acc[M0 + mi][N0 + ni] = __builtin_amdgcn_mfma_f32_16x16x32_bf16(
          a[mi][1], b[N0 + ni][1], acc[M0 + mi][N0 + ni], 0, 0, 0);
    }
}

DEVFN void swz_block(int& bx, int& by, int& bz) {
  long lid = blockIdx.x + (long)gridDim.x * (blockIdx.y + (long)gridDim.y * blockIdx.z);
  const long nwg = (long)gridDim.x * gridDim.y * gridDim.z;
  long s = (nwg % 8 == 0) ? ((lid % 8) * (nwg / 8) + lid / 8) : lid;
  bx = (int)(s % gridDim.x);
  long r2 = s / gridDim.x;
  by = (int)(r2 % gridDim.y);
  bz = (int)(r2 / gridDim.y);
}

template <int OUT_F32>
DEVFN void gemm_body(const GemmP& p, int bx, int by, int bz) {
  const int h = bz / p.NB, n = bz % p.NB;
  const u16* Ab = p.A + (long)h * p.sAh + (long)n * p.sAn;
  const u16* Bb = p.B + (long)h * p.sBh + (long)n * p.sBn;
  const long coff = (long)h * p.sCh + (long)n * p.sCn;
  const int row0 = by * 256;
  const int col0 = bx * 256;

  __shared__ u16 LDSU[65536];  // 128 KiB

  const int tid = threadIdx.x;
  const int wave = tid >> 6, lane = tid & 63;
  const int wr = wave >> 2, wc = wave & 3;
  const int NT = p.K >> 6;

  f32x4 acc[8][4];
  const f32x4 zero = {0.f, 0.f, 0.f, 0.f};
#pragma unroll
  for (int i = 0; i < 8; ++i)
#pragma unroll
    for (int j = 0; j < 4; ++j) acc[i][j] = zero;

  const int swc = ((lane & 7) ^ ((lane >> 3) & 7)) * 8;
  const u16* Ag = Ab + (long)(row0 + wave * 16 + (lane >> 3)) * p.lda + swc;
  const u16* Bg = Bb + (long)(col0 + wave * 16 + (lane >> 3)) * p.ldb + swc;

  auto STAGE = [&](int hh) {
    const int kt = hh >> 2;
    if (kt < NT) {
      const int pt = hh & 3;
      const int hf = pt >> 1;
      u16* l = &LDSU[((pt & 1) ? 32768 : 0) + (kt & 1) * 16384 + hf * 8192 + wave * 1024];
      const int ld = (pt & 1) ? p.ldb : p.lda;
      const u16* g = ((pt & 1) ? Bg : Ag) + (long)hf * 128 * ld + kt * 64;
      gload16(g, l);
      gload16(g + 8L * ld, l + 512);
    }
  };

  STAGE(0); STAGE(1); STAGE(2); STAGE(3); STAGE(4);
  VMCNT2();
  BAR();

  const int rA = lane & 15;
  const int c0 = (((lane >> 4)) ^ (lane & 7)) * 8;
  const int c1 = ((4 + (lane >> 4)) ^ (lane & 7)) * 8;

  bf16x8 a[4][2], b[4][2];

  for (int t = 0; t < NT; ++t) {
    const int db = (t & 1) * 16384;
    const u16* Ar = &LDSU[db + wr * 8192 + rA * 64];
    const u16* Br = &LDSU[32768 + db + (wc >> 1) * 8192 + ((wc & 1) * 64 + rA) * 64];

#pragma unroll
    for (int mi = 0; mi < 4; ++mi) {
      a[mi][0] = *reinterpret_cast<const bf16x8*>(&Ar[mi * 1024 + c0]);
      a[mi][1] = *reinterpret_cast<const bf16x8*>(&Ar[mi * 1024 + c1]);
    }
#pragma unroll
    for (int ni = 0; ni < 2; ++ni) {
      b[ni][0] = *reinterpret_cast<const bf16x8*>(&Br[ni * 1024 + c0]);
      b[ni][1] = *reinterpret_cast<const bf16x8*>(&Br[ni * 1024 + c1]);
    }
    STAGE(4 * t + 5);
    BAR();
    SB0(); __builtin_amdgcn_s_setprio(1);
    quad<0, 0>(acc, a, b);
    __builtin_amdgcn_s_setprio(0); SB0();
    BAR();

#pragma unroll
    for (int ni = 2; ni < 4; ++ni) {
      b[ni][0] = *reinterpret_cast<const bf16x8*>(&Br[ni * 1024 + c0]);
      b[ni][1] = *reinterpret_cast<const bf16x8*>(&Br[ni * 1024 + c1]);
    }
    STAGE(4 * t + 6);
    BAR();
    SB0(); __builtin_amdgcn_s_setprio(1);
    quad<0, 2>(acc, a, b);
    __builtin_amdgcn_s_setprio(0); SB0();
    BAR();

#pragma unroll
    for (int mi = 0; mi < 4; ++mi) {
      a[mi][0] = *reinterpret_cast<const bf16x8*>(&Ar[(4 + mi) * 1024 + c0]);
      a[mi][1] = *reinterpret_cast<const bf16x8*>(&Ar[(4 + mi) * 1024 + c1]);
    }
    STAGE(4 * t + 7);
    BAR();
    SB0(); __builtin_amdgcn_s_setprio(1);
    quad<4, 0>(acc, a, b);
    __builtin_amdgcn_s_setprio(0); SB0();
    BAR();

    STAGE(4 * t + 8);
    if (t < NT - 2) { VMCNT2(); }
    else if (t == NT - 2) { VMCNT0(); }
    BAR();
    SB0(); __builtin_amdgcn_s_setprio(1);
    quad<4, 2>(acc, a, b);
    __builtin_amdgcn_s_setprio(0); SB0();
    BAR();
  }

  const int crow = (lane >> 4) * 4;
  const int ccol = lane & 15;
#pragma unroll
  for (int mi = 0; mi < 8; ++mi) {
#pragma unroll
    for (int j = 0; j < 4; ++j) {
      const int grow = row0 + wr * 128 + mi * 16 + crow + j;
#pragma unroll
      for (int ni = 0; ni < 4; ++ni) {
        const int gcol = col0 + wc * 64 + ni * 16 + ccol;
        float v = acc[mi][ni][j] * p.scale;
        if constexpr (OUT_F32)
          p.Cf[coff + (long)grow * p.ldc + gcol] = v;
        else
          p.Cb[coff + (long)grow * p.ldc + gcol] = f2bf(v);
      }
    }
  }
}

template <int OUT_F32>
__global__ __launch_bounds__(512, 2) void k_gemm256(GemmP p) {
  int bx, by, bz;
  swz_block(bx, by, bz);
  gemm_body<OUT_F32>(p, bx, by, bz);
}
template <int OUT_F32>
__global__ __launch_bounds__(512, 2) void k_gemm256_pair(GemmP2 pp) {
  int bx, by, bz;
  swz_block(bx, by, bz);
  if (bz < pp.split) gemm_body<OUT_F32>(pp.p0, bx, by, bz);
  else gemm_body<OUT_F32>(pp.p1, bx, by, bz - pp.split);
}

// ---------------- FUSED scores+softmax (k_fsc) ------------------------------
// Block: 64 l-rows x 1024 s. 8 waves; wave w owns cols [w*128, w*128+128).
// attn[h][n][l][s] = softmax_s((T·key^T + beta)/32); P = bf16(attn).
// BK=32 double-buffered B (per-wave private 128x32), A staged as 64x64 pairs.
// vmcnt schedule: prologue B0,A0,B1,A1 (18 loads/wave). Even step t: allow
// B(t+1)[8]+A(next)[1]=9 outstanding -> vmcnt(9); odd: vmcnt(8). Stage B(t+2)
// after compute-barrier (WAR-safe); stage A(pair+2) at odd t.
struct FscP {
  const u16* T; const u16* K; const float* beta;
  float* attn; u16* P;
};
__global__ __launch_bounds__(512, 2) void k_fsc(FscP p) {
  int bx, by, bz;
  swz_block(bx, by, bz);
  const int h = by >> 3, n = by & 7;
  const int row0 = bx * 64;

  __shared__ u16 Abuf[2][64][64];      // 16 KB
  __shared__ u16 Bbuf[2][8][128][32];  // 128 KB
  __shared__ float red[2][64][8];      // 4 KB

  const int tid = threadIdx.x;
  const int w = tid >> 6, lane = tid & 63;
  const int rl = lane & 15, g = lane >> 4;

  const u16* Abase = p.T + (long)h * 8388608 + n * 1024 + (long)row0 * 8192;
  const u16* Bbase = p.K + n * 1024;
  const float* betap = p.beta + h * 8192 + n * 1024 + w * 128 + rl;

  float betv[8];
#pragma unroll
  for (int ni = 0; ni < 8; ++ni) betv[ni] = betap[ni * 16];

  f32x4 acc[4][8];
  const f32x4 zero = {0.f, 0.f, 0.f, 0.f};
#pragma unroll
  for (int mi = 0; mi < 4; ++mi)
#pragma unroll
    for (int ni = 0; ni < 8; ++ni) acc[mi][ni] = zero;

  // pre-swizzled global sources (rule 21: inverse-swz source + swz read)
  const u16* Bg = Bbase + (long)(w * 128 + (lane >> 2)) * 8192 +
                  ((lane & 3) ^ ((lane >> 2) & 3)) * 8;
  const u16* Ag = Abase + (long)(w * 8 + (lane >> 3)) * 8192 +
                  ((lane & 7) ^ ((lane >> 3) & 7)) * 8;

  auto STAGE_B = [&](int j) {  // step j, 8 gload16/wave into private region
    u16* l = &Bbuf[j & 1][w][0][0];
    const u16* gp = Bg + (long)j * 32;
#pragma unroll
    for (int i = 0; i < 8; ++i) gload16(gp + (long)i * 16 * 8192, l + i * 512);
  };
  auto STAGE_A = [&](int pp2) {  // pair pp2 (covers steps 2p,2p+1), 1 gload16
    gload16(Ag + (long)pp2 * 64, &Abuf[pp2 & 1][w * 8][0]);
  };

  STAGE_B(0); STAGE_A(0); STAGE_B(1); STAGE_A(1);

  const int cA0 = ((g) ^ (lane & 7)) * 8;
  const int cA1 = ((4 + g) ^ (lane & 7)) * 8;
  const int cB = (g ^ (lane & 3)) * 8;

  for (int t2 = 0; t2 < 16; ++t2) {
    const int pb = t2 & 1;
    // ---- even step t = 2*t2 (B buf 0, A half 0) ----
    VMCNT9();
    BAR();
    {
      bf16x8 aF[4], bF[8];
#pragma unroll
      for (int mi = 0; mi < 4; ++mi)
        aF[mi] = *reinterpret_cast<const bf16x8*>(&Abuf[pb][mi * 16 + rl][cA0]);
#pragma unroll
      for (int ni = 0; ni < 8; ++ni)
        bF[ni] = *reinterpret_cast<const bf16x8*>(&Bbuf[0][w][ni * 16 + rl][cB]);
      SB0(); __builtin_amdgcn_s_setprio(1);
#pragma unroll
      for (int mi = 0; mi < 4; ++mi)
#pragma unroll
        for (int ni = 0; ni < 8; ++ni)
          acc[mi][ni] = __builtin_amdgcn_mfma_f32_16x16x32_bf16(
              aF[mi], bF[ni], acc[mi][ni], 0, 0, 0);
      __builtin_amdgcn_s_setprio(0); SB0();
    }
    BAR();
    if (t2 < 15) STAGE_B(2 * t2 + 2);
    // ---- odd step t = 2*t2+1 (B buf 1, A half 1) ----
    VMCNT8();
    BAR();
    {
      bf16x8 aF[4], bF[8];
#pragma unroll
      for (int mi = 0; mi < 4; ++mi)
        aF[mi] = *reinterpret_cast<const bf16x8*>(&Abuf[pb][mi * 16 + rl][cA1]);
#pragma unroll
      for (int ni = 0; ni < 8; ++ni)
        bF[ni] = *reinterpret_cast<const bf16x8*>(&Bbuf[1][w][ni * 16 + rl][cB]);
      SB0(); __builtin_amdgcn_s_setprio(1);
#pragma unroll
      for (int mi = 0; mi < 4; ++mi)
#pragma unroll
        for (int ni = 0; ni < 8; ++ni)
          acc[mi][ni] = __builtin_amdgcn_mfma_f32_16x16x32_bf16(
              aF[mi], bF[ni], acc[mi][ni], 0, 0, 0);
      __builtin_amdgcn_s_setprio(0); SB0();
    }
    BAR();
    if (t2 < 15) STAGE_B(2 * t2 + 3);
    if (t2 < 14) STAGE_A(t2 + 2);
  }

  // ---- softmax epilogue ----
  // finalize scores: s = (acc + beta[col]) * (1/32); per-row max
  float rmax[4][4];
#pragma unroll
  for (int mi = 0; mi < 4; ++mi)
#pragma unroll
    for (int j = 0; j < 4; ++j) {
      float m = -3.0e38f;
#pragma unroll
      for (int ni = 0; ni < 8; ++ni) {
        float v = (acc[mi][ni][j] + betv[ni]) * 0.03125f;
        acc[mi][ni][j] = v;
        m = fmaxf(m, v);
      }
      rmax[mi][j] = m;
    }
#pragma unroll
  for (int msk = 1; msk < 16; msk <<= 1)
#pragma unroll
    for (int mi = 0; mi < 4; ++mi)
#pragma unroll
      for (int j = 0; j < 4; ++j)
        rmax[mi][j] = fmaxf(rmax[mi][j], __shfl_xor(rmax[mi][j], msk));
  if (rl == 0) {
#pragma unroll
    for (int mi = 0; mi < 4; ++mi)
#pragma unroll
      for (int j = 0; j < 4; ++j) red[0][mi * 16 + g * 4 + j][w] = rmax[mi][j];
  }
  __syncthreads();
  float gmax[4][4];
#pragma unroll
  for (int mi = 0; mi < 4; ++mi)
#pragma unroll
    for (int j = 0; j < 4; ++j) {
      const int row = mi * 16 + g * 4 + j;
      float4 x = *reinterpret_cast<const float4*>(&red[0][row][0]);
      float4 y = *reinterpret_cast<const float4*>(&red[0][row][4]);
      gmax[mi][j] = fmaxf(fmaxf(fmaxf(x.x, x.y), fmaxf(x.z, x.w)),
                          fmaxf(fmaxf(y.x, y.y), fmaxf(y.z, y.w)));
    }
  // exp + row-sum
  float rsum[4][4];
#pragma unroll
  for (int mi = 0; mi < 4; ++mi)
#pragma unroll
    for (int j = 0; j < 4; ++j) {
      float s = 0.f;
#pragma unroll
      for (int ni = 0; ni < 8; ++ni) {
        float e = __expf(acc[mi][ni][j] - gmax[mi][j]);
        acc[mi][ni][j] = e;
        s += e;
      }
      rsum[mi][j] = s;
    }
#pragma unroll
  for (int msk = 1; msk < 16; msk <<= 1)
#pragma unroll
    for (int mi = 0; mi < 4; ++mi)
#pragma unroll
      for (int j = 0; j < 4; ++j) rsum[mi][j] += __shfl_xor(rsum[mi][j], msk);
  if (rl == 0) {
#pragma unroll
    for (int mi = 0; mi < 4; ++mi)
#pragma unroll
      for (int j = 0; j < 4; ++j) red[1][mi * 16 + g * 4 + j][w] = rsum[mi][j];
  }
  __syncthreads();
  float* attn_b = p.attn + ((long)h * 8 + n) * 1048576;
  u16* P_b = p.P + ((long)h * 8 + n) * 1048576;
#pragma unroll
  for (int mi = 0; mi < 4; ++mi)
#pragma unroll
    for (int j = 0; j < 4; ++j) {
      const int row = mi * 16 + g * 4 + j;
      float4 x = *reinterpret_cast<const float4*>(&red[1][row][0]);
      float4 y = *reinterpret_cast<const float4*>(&red[1][row][4]);
      const float inv =
          1.0f / (x.x + x.y + x.z + x.w + y.x + y.y + y.z + y.w);
      float* ar = attn_b + (long)(row0 + row) * 1024 + w * 128 + rl;
      u16* pr = P_b + (long)(row0 + row) * 1024 + w * 128 + rl;
#pragma unroll
      for (int ni = 0; ni < 8; ++ni) {
        float v = acc[mi][ni][j] * inv;
        ar[ni * 16] = v;
        pr[ni * 16] = f2bf(v);
      }
    }
}

// ============================================================================
extern "C" void kernel_launch(void* const* d_in, const int* in_sizes, int n_in,
                              void* d_out, int out_size, void* d_ws,
                              size_t ws_size, hipStream_t stream) {
  const float* query = (const float*)d_in[0];
  const float* key_  = (const float*)d_in[1];
  const float* value = (const float*)d_in[2];
  const float* Wqkv  = (const float*)d_in[3];
  const float* bqkv  = (const float*)d_in[4];
  const float* Wo    = (const float*)d_in[5];
  const float* bo    = (const float*)d_in[6];
  const float* Wout  = (const float*)d_in[7];
  const float* bout  = (const float*)d_in[8];

  float* out  = (float*)d_out;
  float* attn = out + LNE;  // (H,N,L,S) f32

  u16* ws = (u16*)d_ws;
  u16* qbf   = ws + OF_QBF;
  u16* kbf   = ws + OF_KBF;
  u16* valT  = ws + OF_VALT;
  u16* WqT_F = ws + OF_F;
  u16* WkT   = ws + OF_WKT;
  u16* WvT   = ws + OF_WVT;
  u16* WoT   = ws + OF_WOT;
  u16* Woutb = ws + OF_WOUTB;
  u16* Gt    = ws + OF_GT;
  u16* Bm    = ws + OF_BM;
  u16* Tbuf  = ws + OF_T;    // T, then U
  u16* Pbuf  = ws + OF_P;    // P, then split-K partials (f32)
  float* part = (float*)(ws + OF_P);
  float* Sf   = (float*)d_ws + OF_SMALL_F;
  float* beta  = Sf;            // 65536
  float* bv2   = Sf + 65536;    // 8192
  float* be2   = Sf + 73728;    // 1024
  float* bpart = Sf + 74752;    // 65536

  // ---- converts ----
  {
    Cvt3P p;
    p.s[0] = query; p.s[1] = key_; p.s[2] = Wout;
    p.d[0] = qbf;   p.d[1] = kbf;  p.d[2] = Woutb;
    k_cvt3<<<dim3(512, 3), 256, 0, stream>>>(p);
  }
  {
    Tp5P p;
    p.s[0] = Wqkv;           p.d[0] = WqT_F; p.sld[0] = 1024; p.szs[0] = 3145728; p.dzs[0] = MM;
    p.s[1] = Wqkv + 1048576; p.d[1] = WkT;   p.sld[1] = 1024; p.szs[1] = 3145728; p.dzs[1] = MM;
    p.s[2] = Wqkv + 2097152; p.d[2] = WvT;   p.sld[2] = 1024; p.szs[2] = 3145728; p.dzs[2] = MM;
    p.s[3] = Wo;             p.d[3] = WoT;   p.sld[3] = 1024; p.szs[3] = MM;      p.dzs[3] = MM;
    p.s[4] = value;          p.d[4] = valT;  p.sld[4] = 8192; p.szs[4] = 1024;    p.dzs[4] = MM;
    k_tp5<<<dim3(16, 16, 40), 256, 0, stream>>>(p);
  }
  // ---- beta precompute ----
  k_bvec<<<dim3(4, 8, 8), 256, 0, stream>>>(Wqkv, bqkv, bpart);
  k_redb<<<32, 256, 0, stream>>>(bpart, bv2);
  k_rowdot<<<2048, 256, 0, stream>>>(key_, bv2, beta);

  const dim3 blk(512);

  // ---- Gt = WkT·WqT^T  and  Bm = Woutb·WoT^T ----
  {
    GemmP g = {};
    g.A = WkT; g.lda = 1024; g.sAh = MM; g.sAn = 0;
    g.B = WqT_F; g.ldb = 1024; g.sBh = MM; g.sBn = 0;
    g.Cb = Gt; g.ldc = 1024; g.sCh = MM; g.sCn = 0;
    g.K = 1024; g.NB = 1; g.scale = 1.f;
    GemmP m = {};
    m.A = Woutb; m.lda = 8192; m.sAh = 1024; m.sAn = 0;
    m.B = WoT; m.ldb = 1024; m.sBh = MM; m.sBn = 0;
    m.Cb = Bm; m.ldc = 8192; m.sCh = 1024; m.sCn = 0;
    m.K = 1024; m.NB = 1; m.scale = 1.f;
    GemmP2 pp = {g, m, 8};
    k_gemm256_pair<0><<<dim3(4, 4, 16), blk, 0, stream>>>(pp);
  }
  k_be2<<<1024, 256, 0, stream>>>(Wout, bo, bout, bqkv, Bm, be2);
  // ---- T = qbf·Gt^T (z<64) and F = Bm·WvT^T (z>=64) ----
  {
    GemmP t = {};
    t.A = qbf; t.lda = 8192; t.sAh = 0; t.sAn = 1024;
    t.B = Gt; t.ldb = 1024; t.sBh = MM; t.sBn = 0;
    t.Cb = Tbuf; t.ldc = 8192; t.sCh = 8388608; t.sCn = 1024;
    t.K = 1024; t.NB = 8; t.scale = 1.f;
    GemmP f = {};
    f.A = Bm; f.lda = 8192; f.sAh = 1024; f.sAn = 0;
    f.B = WvT; f.ldb = 1024; f.sBh = MM; f.sBn = 0;
    f.Cb = WqT_F; f.ldc = 8192; f.sCh = 1024; f.sCn = 0;
    f.K = 1024; f.NB = 1; f.scale = 1.f;
    GemmP2 pp = {t, f, 64};
    k_gemm256_pair<0><<<dim3(4, 4, 72), blk, 0, stream>>>(pp);
  }
  // ---- FUSED scores+softmax -> attn f32 + P bf16 ----
  {
    FscP p = {Tbuf, kbf, beta, attn, Pbuf};
    k_fsc<<<dim3(16, 64), blk, 0, stream>>>(p);
  }
  // ---- U = P·valT^T  (into Tbuf slot; T dead) ----
  {
    GemmP p = {};
    p.A = Pbuf; p.lda = 1024; p.sAh = 8388608; p.sAn = 1048576;
    p.B = valT; p.ldb = 1024; p.sBh = 0; p.sBn = 1048576;
    p.Cb = Tbuf; p.ldc = 65536; p.sCh = 1024; p.sCn = 8192;
    p.K = 1024; p.NB = 8; p.scale = 1.f;
    k_gemm256<0><<<dim3(4, 4, 64), blk, 0, stream>>>(p);
  }
  // ---- out partials split-K=4 (into Pbuf slot; P dead) ----
  {
    GemmP p = {};
    p.A = Tbuf; p.lda = 8192; p.sAh = 2048; p.sAn = 0;
    p.B = WqT_F; p.ldb = 8192; p.sBh = 2048; p.sBn = 0;
    p.Cf = part; p.ldc = 1024; p.sCh = 8388608; p.sCn = 0;
    p.K = 2048; p.NB = 1; p.scale = 1.f;
    k_gemm256<1><<<dim3(4, 32, 4), blk, 0, stream>>>(p);
  }
  k_combine4<<<2048, 256, 0, stream>>>(part, be2, out);
}